// Round 1
// baseline (564.603 us; speedup 1.0000x reference)
//
#include <hip/hip_runtime.h>
#include <cstdint>

#define D 128
#define NEG 0.2f

__device__ __forceinline__ float wsum(float v){
#pragma unroll
  for(int m=32;m;m>>=1) v += __shfl_xor(v,m,64);
  return v;
}
__device__ __forceinline__ float wmax(float v){
#pragma unroll
  for(int m=32;m;m>>=1) v = fmaxf(v,__shfl_xor(v,m,64));
  return v;
}
__device__ __forceinline__ float lrelu(float a){ return a>0.f ? a : NEG*a; }

// ---- K1: we_ae[l][s] = dot(We_l[s,:], ae_l)  (256 waves, one per row) ----
__global__ __launch_bounds__(256) void k_weae(const float* __restrict__ We1, const float* __restrict__ ae1,
                                              const float* __restrict__ We2, const float* __restrict__ ae2,
                                              float* __restrict__ weae){
  int gw  = (blockIdx.x*blockDim.x + threadIdx.x) >> 6;
  int lane = threadIdx.x & 63;
  if (gw >= 256) return;
  const float* We = (gw & 128) ? We2 : We1;
  const float* ae = (gw & 128) ? ae2 : ae1;
  int row = gw & 127;
  float2 v = ((const float2*)(We + (size_t)row*D))[lane];
  float2 a = ((const float2*)ae)[lane];
  float p = wsum(v.x*a.x + v.y*a.y);
  if (!lane) weae[gw] = p;
}

// ---- K2: one pass over edge_attr (410MB): per-edge a_e for BOTH layers,
//          plus deg histogram and per-dst sums (for self-loop mean attr) ----
__global__ __launch_bounds__(256) void k_edge(const float* __restrict__ EA, const int* __restrict__ dstv,
                                              const float* __restrict__ weae,
                                              float* __restrict__ o1, float* __restrict__ o2,
                                              float* __restrict__ sum1, float* __restrict__ sum2,
                                              int* __restrict__ deg, int E){
  __shared__ float w1[128], w2[128];
  if (threadIdx.x < 128) w1[threadIdx.x] = weae[threadIdx.x];
  else                   w2[threadIdx.x-128] = weae[threadIdx.x];
  __syncthreads();
  int lane = threadIdx.x & 63;
  int wid  = threadIdx.x >> 6;
  float2 wa = ((const float2*)w1)[lane];
  float2 wb = ((const float2*)w2)[lane];
  for (int e = blockIdx.x*4 + wid; e < E; e += gridDim.x*4){
    float2 v = ((const float2*)(EA + (size_t)e*D))[lane];
    float s1 = wsum(v.x*wa.x + v.y*wa.y);
    float s2 = wsum(v.x*wb.x + v.y*wb.y);
    if (!lane){
      o1[e] = s1; o2[e] = s2;
      int d = dstv[e];
      atomicAdd(deg + d, 1);
      atomicAdd(sum1 + d, s1);
      atomicAdd(sum2 + d, s2);
    }
  }
}

// ---- scan: deg -> row_ptr (exclusive), 3 kernels ----
__global__ __launch_bounds__(256) void k_scan1(const int* __restrict__ deg, int* __restrict__ bsum, int N){
  __shared__ int s[256];
  int i = blockIdx.x*256 + threadIdx.x;
  s[threadIdx.x] = (i < N) ? deg[i] : 0;
  __syncthreads();
#pragma unroll
  for (int st = 128; st; st >>= 1){
    if (threadIdx.x < st) s[threadIdx.x] += s[threadIdx.x + st];
    __syncthreads();
  }
  if (!threadIdx.x) bsum[blockIdx.x] = s[0];
}
__global__ __launch_bounds__(256) void k_scan2(const int* __restrict__ bsum, int* __restrict__ boff, int NB){
  __shared__ int s[256];
  int t = threadIdx.x;
  int v = (t < NB) ? bsum[t] : 0;
  s[t] = v; __syncthreads();
  for (int d = 1; d < 256; d <<= 1){
    int x = (t >= d) ? s[t-d] : 0;
    __syncthreads();
    s[t] += x;
    __syncthreads();
  }
  boff[t] = s[t] - v;   // exclusive
}
__global__ __launch_bounds__(256) void k_scan3(const int* __restrict__ deg, const int* __restrict__ boff,
                                               int* __restrict__ rowp, int N, int E){
  __shared__ int s[256];
  int t = threadIdx.x;
  int i = blockIdx.x*256 + t;
  int v = (i < N) ? deg[i] : 0;
  s[t] = v; __syncthreads();
  for (int d = 1; d < 256; d <<= 1){
    int x = (t >= d) ? s[t-d] : 0;
    __syncthreads();
    s[t] += x;
    __syncthreads();
  }
  if (i < N) rowp[i] = boff[blockIdx.x] + s[t] - v;
  if (i == N-1) rowp[N] = E;
}

// ---- CSR fill ----
__global__ __launch_bounds__(256) void k_csr(const int* __restrict__ srcv, const int* __restrict__ dstv,
                                             const int* __restrict__ rowp, int* __restrict__ cursor,
                                             int* __restrict__ cse, int* __restrict__ css, int E){
  int e = blockIdx.x*256 + threadIdx.x;
  if (e >= E) return;
  int d = dstv[e];
  int pos = rowp[d] + atomicAdd(cursor + d, 1);
  cse[pos] = e;
  css[pos] = srcv[e];
}

// ---- GEMM: H[N,128] = X[N,128] @ W[128,128], fp32, 32-row tiles, 4x4 reg blocking ----
__global__ __launch_bounds__(256) void k_gemm(const float* __restrict__ X, const float* __restrict__ W,
                                              float* __restrict__ H, int N){
  __shared__ float ws_[128][128];  // 64KB
  __shared__ float xs[32][128];    // 16KB
  int tid = threadIdx.x;
  const float4* W4 = (const float4*)W;
  float4* wsv = (float4*)&ws_[0][0];
#pragma unroll
  for (int i = 0; i < 16; ++i) wsv[tid + i*256] = W4[tid + i*256];
  int row0 = blockIdx.x*32;
  float4* xsv = (float4*)&xs[0][0];
  const float4* X4 = (const float4*)X;
#pragma unroll
  for (int i = 0; i < 4; ++i){
    int idx = tid + i*256;
    int r = idx >> 5, c = idx & 31;
    float4 v = {0.f,0.f,0.f,0.f};
    int gr = row0 + r;
    if (gr < N) v = X4[(size_t)gr*32 + c];
    xsv[idx] = v;
  }
  __syncthreads();
  int tc = tid & 31, tr = tid >> 5;
  float acc[4][4];
#pragma unroll
  for (int i = 0; i < 4; ++i)
#pragma unroll
    for (int j = 0; j < 4; ++j) acc[i][j] = 0.f;
#pragma unroll 4
  for (int k = 0; k < 128; ++k){
    float4 wv = *(const float4*)&ws_[k][tc*4];
    float xv[4];
#pragma unroll
    for (int i = 0; i < 4; ++i) xv[i] = xs[tr*4 + i][k];
#pragma unroll
    for (int i = 0; i < 4; ++i){
      acc[i][0] += xv[i]*wv.x;
      acc[i][1] += xv[i]*wv.y;
      acc[i][2] += xv[i]*wv.z;
      acc[i][3] += xv[i]*wv.w;
    }
  }
#pragma unroll
  for (int i = 0; i < 4; ++i){
    int gr = row0 + tr*4 + i;
    if (gr < N){
      float4 o = {acc[i][0], acc[i][1], acc[i][2], acc[i][3]};
      ((float4*)H)[(size_t)gr*32 + tc] = o;
    }
  }
}

// ---- a_s, a_d per node + self-loop alpha (one wave per node) ----
__global__ __launch_bounds__(256) void k_asad(const float* __restrict__ H,
                                              const float* __restrict__ atts, const float* __restrict__ attd,
                                              const float* __restrict__ sum_ae, const int* __restrict__ deg,
                                              float* __restrict__ a_s, float* __restrict__ a_d,
                                              float* __restrict__ sal, int N){
  int wid  = (blockIdx.x*blockDim.x + threadIdx.x) >> 6;
  int lane = threadIdx.x & 63;
  if (wid >= N) return;
  float2 hv = ((const float2*)(H + (size_t)wid*D))[lane];
  float2 s2 = ((const float2*)atts)[lane];
  float2 d2 = ((const float2*)attd)[lane];
  float ps = hv.x*s2.x + hv.y*s2.y;
  float pd = hv.x*d2.x + hv.y*d2.y;
#pragma unroll
  for (int m = 32; m; m >>= 1){ ps += __shfl_xor(ps,m,64); pd += __shfl_xor(pd,m,64); }
  if (!lane){
    a_s[wid] = ps; a_d[wid] = pd;
    float la = sum_ae[wid] / fmaxf((float)deg[wid], 1.0f);
    sal[wid] = lrelu(ps + pd + la);
  }
}

// ---- per-edge alpha (leaky-relu'd), edge order ----
__global__ __launch_bounds__(256) void k_alpha(const int* __restrict__ srcv, const int* __restrict__ dstv,
                                               const float* __restrict__ a_s, const float* __restrict__ a_d,
                                               const float* __restrict__ aeE, float* __restrict__ alE, int E){
  int e = blockIdx.x*256 + threadIdx.x;
  if (e >= E) return;
  alE[e] = lrelu(a_s[srcv[e]] + a_d[dstv[e]] + aeE[e]);
}

// ---- aggregation: one wave per dst node; softmax + weighted gather of h[src] ----
__global__ __launch_bounds__(256) void k_aggr(const float* __restrict__ H, const float* __restrict__ alE,
                                              const float* __restrict__ sal,
                                              const int* __restrict__ rowp, const int* __restrict__ cse,
                                              const int* __restrict__ css,
                                              const float* __restrict__ bias, float* __restrict__ OUT,
                                              int N, int relu){
  int wid  = (blockIdx.x*blockDim.x + threadIdx.x) >> 6;
  int lane = threadIdx.x & 63;
  if (wid >= N) return;
  int p0 = rowp[wid], p1 = rowp[wid+1];
  float sa = sal[wid];
  float m = sa;
  for (int p = p0 + lane; p < p1; p += 64) m = fmaxf(m, alE[cse[p]]);
  m = wmax(m);
  // self-loop contribution
  float ex = __expf(sa - m);
  float2 hv = ((const float2*)(H + (size_t)wid*D))[lane];
  float ax = ex*hv.x, ay = ex*hv.y;
  float denom = ex;
  for (int p = p0; p < p1; ++p){
    int eid = cse[p];
    int s   = css[p];
    float w = __expf(alE[eid] - m);
    float2 h2 = ((const float2*)(H + (size_t)s*D))[lane];
    ax += w*h2.x; ay += w*h2.y; denom += w;
  }
  float2 bv = ((const float2*)bias)[lane];
  float inv = 1.0f/denom;
  float ox = ax*inv + bv.x, oy = ay*inv + bv.y;
  if (relu){ ox = fmaxf(ox, 0.f); oy = fmaxf(oy, 0.f); }
  ((float2*)(OUT + (size_t)wid*D))[lane] = make_float2(ox, oy);
}

extern "C" void kernel_launch(void* const* d_in, const int* in_sizes, int n_in,
                              void* d_out, int out_size, void* d_ws, size_t ws_size,
                              hipStream_t stream){
  (void)n_in; (void)out_size; (void)ws_size;
  const float* x   = (const float*)d_in[0];
  const int*   ei  = (const int*)d_in[1];
  const float* ea  = (const float*)d_in[2];
  const float* W1  = (const float*)d_in[3];
  const float* a1s = (const float*)d_in[4];
  const float* a1d = (const float*)d_in[5];
  const float* We1 = (const float*)d_in[6];
  const float* ae1 = (const float*)d_in[7];
  const float* b1  = (const float*)d_in[8];
  const float* W2  = (const float*)d_in[9];
  const float* a2s = (const float*)d_in[10];
  const float* a2d = (const float*)d_in[11];
  const float* We2 = (const float*)d_in[12];
  const float* ae2 = (const float*)d_in[13];
  const float* b2  = (const float*)d_in[14];
  int N = in_sizes[0] / D;
  int E = in_sizes[1] / 2;
  const int* srcv = ei;
  const int* dstv = ei + E;
  float* out = (float*)d_out;

  char* p = (char*)d_ws;
  auto alloc = [&](size_t elems)->void*{
    void* r = (void*)p; p += ((elems*4 + 255)/256)*256; return r;
  };
  float* h    = (float*)alloc((size_t)N*D);
  float* x2   = (float*)alloc((size_t)N*D);
  float* aeE1 = (float*)alloc(E);
  float* aeE2 = (float*)alloc(E);
  float* alE  = (float*)alloc(E);
  float* as_  = (float*)alloc(N);
  float* ad_  = (float*)alloc(N);
  float* sal  = (float*)alloc(N);
  float* sum1 = (float*)alloc(N);
  float* sum2 = (float*)alloc(N);
  float* weae = (float*)alloc(256);
  int* deg    = (int*)alloc(N);
  int* cursor = (int*)alloc(N);
  int* rowp   = (int*)alloc(N+1);
  int* cse    = (int*)alloc(E);
  int* css    = (int*)alloc(E);
  int* bsum   = (int*)alloc(256);
  int* boff   = (int*)alloc(256);

  hipMemsetAsync(deg,    0, (size_t)N*4, stream);
  hipMemsetAsync(cursor, 0, (size_t)N*4, stream);
  hipMemsetAsync(sum1,   0, (size_t)N*4, stream);
  hipMemsetAsync(sum2,   0, (size_t)N*4, stream);

  k_weae<<<64,256,0,stream>>>(We1,ae1,We2,ae2,weae);
  k_edge<<<2048,256,0,stream>>>(ea,dstv,weae,aeE1,aeE2,sum1,sum2,deg,E);

  int nb = (N + 255)/256;
  k_scan1<<<nb,256,0,stream>>>(deg,bsum,N);
  k_scan2<<<1,256,0,stream>>>(bsum,boff,nb);
  k_scan3<<<nb,256,0,stream>>>(deg,boff,rowp,N,E);
  k_csr<<<(E+255)/256,256,0,stream>>>(srcv,dstv,rowp,cursor,cse,css,E);

  int gemmb = (N + 31)/32;
  int wgrid = (N + 3)/4;

  // layer 1
  k_gemm<<<gemmb,256,0,stream>>>(x, W1, h, N);
  k_asad<<<wgrid,256,0,stream>>>(h, a1s, a1d, sum1, deg, as_, ad_, sal, N);
  k_alpha<<<(E+255)/256,256,0,stream>>>(srcv, dstv, as_, ad_, aeE1, alE, E);
  k_aggr<<<wgrid,256,0,stream>>>(h, alE, sal, rowp, cse, css, b1, x2, N, 1);

  // layer 2
  k_gemm<<<gemmb,256,0,stream>>>(x2, W2, h, N);
  k_asad<<<wgrid,256,0,stream>>>(h, a2s, a2d, sum2, deg, as_, ad_, sal, N);
  k_alpha<<<(E+255)/256,256,0,stream>>>(srcv, dstv, as_, ad_, aeE2, alE, E);
  k_aggr<<<wgrid,256,0,stream>>>(h, alE, sal, rowp, cse, css, b2, out, N, 0);
}

// Round 2
// 523.406 us; speedup vs baseline: 1.0787x; 1.0787x over previous
//
#include <hip/hip_runtime.h>
#include <cstdint>

#define D 128
#define NEG 0.2f

__device__ __forceinline__ float wsum(float v){
#pragma unroll
  for(int m=32;m;m>>=1) v += __shfl_xor(v,m,64);
  return v;
}
__device__ __forceinline__ float wmax(float v){
#pragma unroll
  for(int m=32;m;m>>=1) v = fmaxf(v,__shfl_xor(v,m,64));
  return v;
}
__device__ __forceinline__ float hsum32(float v){
#pragma unroll
  for(int m=16;m;m>>=1) v += __shfl_xor(v,m,64);
  return v;
}
__device__ __forceinline__ float lrelu(float a){ return a>0.f ? a : NEG*a; }

// ---- we_ae[l][s] = dot(We_l[s,:], ae_l) ----
__global__ __launch_bounds__(256) void k_weae(const float* __restrict__ We1, const float* __restrict__ ae1,
                                              const float* __restrict__ We2, const float* __restrict__ ae2,
                                              float* __restrict__ weae){
  int gw  = (blockIdx.x*blockDim.x + threadIdx.x) >> 6;
  int lane = threadIdx.x & 63;
  if (gw >= 256) return;
  const float* We = (gw & 128) ? We2 : We1;
  const float* ae = (gw & 128) ? ae2 : ae1;
  int row = gw & 127;
  float2 v = ((const float2*)(We + (size_t)row*D))[lane];
  float2 a = ((const float2*)ae)[lane];
  float p = wsum(v.x*a.x + v.y*a.y);
  if (!lane) weae[gw] = p;
}

// ---- one pass over edge_attr (410MB): per-edge a_e for both layers + deg + per-dst a_e sums ----
__global__ __launch_bounds__(256) void k_edge(const float* __restrict__ EA, const int* __restrict__ dstv,
                                              const float* __restrict__ weae,
                                              float* __restrict__ o1, float* __restrict__ o2,
                                              float* __restrict__ sum1, float* __restrict__ sum2,
                                              int* __restrict__ deg, int E){
  __shared__ float w1[128], w2[128];
  if (threadIdx.x < 128) w1[threadIdx.x] = weae[threadIdx.x];
  else                   w2[threadIdx.x-128] = weae[threadIdx.x];
  __syncthreads();
  int lane = threadIdx.x & 63;
  int wid  = threadIdx.x >> 6;
  float2 wa = ((const float2*)w1)[lane];
  float2 wb = ((const float2*)w2)[lane];
  for (int e = blockIdx.x*4 + wid; e < E; e += gridDim.x*4){
    float2 v = ((const float2*)(EA + (size_t)e*D))[lane];
    float s1 = wsum(v.x*wa.x + v.y*wa.y);
    float s2 = wsum(v.x*wb.x + v.y*wb.y);
    if (!lane){
      o1[e] = s1; o2[e] = s2;
      int d = dstv[e];
      atomicAdd(deg + d, 1);
      atomicAdd(sum1 + d, s1);
      atomicAdd(sum2 + d, s2);
    }
  }
}

// ---- scan: deg -> row_ptr (exclusive) ----
__global__ __launch_bounds__(256) void k_scan1(const int* __restrict__ deg, int* __restrict__ bsum, int N){
  __shared__ int s[256];
  int i = blockIdx.x*256 + threadIdx.x;
  s[threadIdx.x] = (i < N) ? deg[i] : 0;
  __syncthreads();
#pragma unroll
  for (int st = 128; st; st >>= 1){
    if (threadIdx.x < st) s[threadIdx.x] += s[threadIdx.x + st];
    __syncthreads();
  }
  if (!threadIdx.x) bsum[blockIdx.x] = s[0];
}
__global__ __launch_bounds__(256) void k_scan2(const int* __restrict__ bsum, int* __restrict__ boff, int NB){
  __shared__ int s[256];
  int t = threadIdx.x;
  int v = (t < NB) ? bsum[t] : 0;
  s[t] = v; __syncthreads();
  for (int d = 1; d < 256; d <<= 1){
    int x = (t >= d) ? s[t-d] : 0;
    __syncthreads();
    s[t] += x;
    __syncthreads();
  }
  boff[t] = s[t] - v;
}
__global__ __launch_bounds__(256) void k_scan3(const int* __restrict__ deg, const int* __restrict__ boff,
                                               int* __restrict__ rowp, int N, int E){
  __shared__ int s[256];
  int t = threadIdx.x;
  int i = blockIdx.x*256 + t;
  int v = (i < N) ? deg[i] : 0;
  s[t] = v; __syncthreads();
  for (int d = 1; d < 256; d <<= 1){
    int x = (t >= d) ? s[t-d] : 0;
    __syncthreads();
    s[t] += x;
    __syncthreads();
  }
  if (i < N) rowp[i] = boff[blockIdx.x] + s[t] - v;
  if (i == N-1) rowp[N] = E;
}

// ---- CSR fill: src + dst-sorted per-edge attention scalars (both layers) ----
__global__ __launch_bounds__(256) void k_csr(const int* __restrict__ srcv, const int* __restrict__ dstv,
                                             const int* __restrict__ rowp, int* __restrict__ cursor,
                                             int* __restrict__ css,
                                             const float* __restrict__ ae1, const float* __restrict__ ae2,
                                             float* __restrict__ ae1s, float* __restrict__ ae2s, int E){
  int e = blockIdx.x*256 + threadIdx.x;
  if (e >= E) return;
  int d = dstv[e];
  int pos = rowp[d] + atomicAdd(cursor + d, 1);
  css[pos]  = srcv[e];
  ae1s[pos] = ae1[e];
  ae2s[pos] = ae2[e];
}

// ---- GEMM + fused a_s/a_d/self-loop-alpha epilogue ----
// H[N,128] = X @ W;  a_s=H@atts, a_d=H@attd, sal=lrelu(a_s+a_d+sum_ae/deg)
__global__ __launch_bounds__(256) void k_gemm(const float* __restrict__ X, const float* __restrict__ W,
                                              const float* __restrict__ atts, const float* __restrict__ attd,
                                              const float* __restrict__ sum_ae, const int* __restrict__ deg,
                                              float* __restrict__ H, float* __restrict__ a_s,
                                              float* __restrict__ a_d, float* __restrict__ sal, int N){
  __shared__ float ws_[64][128];   // 32KB: one k-half of W, [k][c]
  __shared__ float xs[32][132];    // 16.9KB padded
  int tid = threadIdx.x;
  int row0 = blockIdx.x*32;
  const float4* X4 = (const float4*)X;
#pragma unroll
  for (int i = 0; i < 4; ++i){
    int idx = tid + i*256;
    int r = idx >> 5, c = idx & 31;
    float4 v = {0.f,0.f,0.f,0.f};
    int gr = row0 + r;
    if (gr < N) v = X4[(size_t)gr*32 + c];
    *(float4*)&xs[r][c*4] = v;
  }
  int tc = tid & 31, tr = tid >> 5;
  float acc[4][4];
#pragma unroll
  for (int i=0;i<4;++i)
#pragma unroll
    for (int j=0;j<4;++j) acc[i][j]=0.f;

  const float4* W4 = (const float4*)W;
  for (int kh = 0; kh < 2; ++kh){
    __syncthreads();
#pragma unroll
    for (int i = 0; i < 8; ++i){
      int idx = tid + i*256;
      int r = idx >> 5, c = idx & 31;
      *(float4*)&ws_[r][c*4] = W4[(size_t)(kh*64 + r)*32 + c];
    }
    __syncthreads();
#pragma unroll 2
    for (int k0 = 0; k0 < 64; k0 += 4){
      float4 a0 = *(const float4*)&xs[tr     ][kh*64 + k0];
      float4 a1 = *(const float4*)&xs[tr + 8 ][kh*64 + k0];
      float4 a2 = *(const float4*)&xs[tr + 16][kh*64 + k0];
      float4 a3 = *(const float4*)&xs[tr + 24][kh*64 + k0];
      float A0[4]={a0.x,a0.y,a0.z,a0.w}, A1[4]={a1.x,a1.y,a1.z,a1.w};
      float A2[4]={a2.x,a2.y,a2.z,a2.w}, A3[4]={a3.x,a3.y,a3.z,a3.w};
#pragma unroll
      for (int kk = 0; kk < 4; ++kk){
        float4 bv = *(const float4*)&ws_[k0+kk][tc*4];
        acc[0][0]+=A0[kk]*bv.x; acc[0][1]+=A0[kk]*bv.y; acc[0][2]+=A0[kk]*bv.z; acc[0][3]+=A0[kk]*bv.w;
        acc[1][0]+=A1[kk]*bv.x; acc[1][1]+=A1[kk]*bv.y; acc[1][2]+=A1[kk]*bv.z; acc[1][3]+=A1[kk]*bv.w;
        acc[2][0]+=A2[kk]*bv.x; acc[2][1]+=A2[kk]*bv.y; acc[2][2]+=A2[kk]*bv.z; acc[2][3]+=A2[kk]*bv.w;
        acc[3][0]+=A3[kk]*bv.x; acc[3][1]+=A3[kk]*bv.y; acc[3][2]+=A3[kk]*bv.z; acc[3][3]+=A3[kk]*bv.w;
      }
    }
  }
  // epilogue: write H + fused a_s/a_d/sal
  float4 sv = ((const float4*)atts)[tc];
  float4 dv = ((const float4*)attd)[tc];
#pragma unroll
  for (int i = 0; i < 4; ++i){
    int gr = row0 + tr + 8*i;
    float ps = acc[i][0]*sv.x + acc[i][1]*sv.y + acc[i][2]*sv.z + acc[i][3]*sv.w;
    float pd = acc[i][0]*dv.x + acc[i][1]*dv.y + acc[i][2]*dv.z + acc[i][3]*dv.w;
    ps = hsum32(ps); pd = hsum32(pd);
    if (gr < N){
      ((float4*)H)[(size_t)gr*32 + tc] = make_float4(acc[i][0],acc[i][1],acc[i][2],acc[i][3]);
      if (tc == 0){
        a_s[gr] = ps; a_d[gr] = pd;
        float la = sum_ae[gr] / fmaxf((float)deg[gr], 1.0f);
        sal[gr] = lrelu(ps + pd + la);
      }
    }
  }
}

// ---- aggregation: one wave per dst; alpha computed on the fly; softmax + weighted h gather ----
__global__ __launch_bounds__(256) void k_aggr(const float* __restrict__ H, const float* __restrict__ a_s,
                                              const float* __restrict__ a_d, const float* __restrict__ sal,
                                              const int* __restrict__ rowp, const int* __restrict__ css,
                                              const float* __restrict__ aes,
                                              const float* __restrict__ bias, float* __restrict__ OUT,
                                              int N, int relu){
  int wid  = (blockIdx.x*blockDim.x + threadIdx.x) >> 6;
  int lane = threadIdx.x & 63;
  if (wid >= N) return;
  int p0 = rowp[wid], p1 = rowp[wid+1];
  float ad = a_d[wid];
  float sa = sal[wid];
  float m = sa;
  for (int p = p0 + lane; p < p1; p += 64)
    m = fmaxf(m, lrelu(a_s[css[p]] + ad + aes[p]));
  m = wmax(m);
  float ex = __expf(sa - m);
  float2 hv = ((const float2*)(H + (size_t)wid*D))[lane];
  float ax = ex*hv.x, ay = ex*hv.y, denom = ex;
  for (int p = p0; p < p1; ++p){
    int s = css[p];
    float w = __expf(lrelu(a_s[s] + ad + aes[p]) - m);
    float2 h2 = ((const float2*)(H + (size_t)s*D))[lane];
    ax += w*h2.x; ay += w*h2.y; denom += w;
  }
  float2 bv = ((const float2*)bias)[lane];
  float inv = 1.0f/denom;
  float ox = ax*inv + bv.x, oy = ay*inv + bv.y;
  if (relu){ ox = fmaxf(ox, 0.f); oy = fmaxf(oy, 0.f); }
  ((float2*)(OUT + (size_t)wid*D))[lane] = make_float2(ox, oy);
}

extern "C" void kernel_launch(void* const* d_in, const int* in_sizes, int n_in,
                              void* d_out, int out_size, void* d_ws, size_t ws_size,
                              hipStream_t stream){
  (void)n_in; (void)out_size; (void)ws_size;
  const float* x   = (const float*)d_in[0];
  const int*   ei  = (const int*)d_in[1];
  const float* ea  = (const float*)d_in[2];
  const float* W1  = (const float*)d_in[3];
  const float* a1s = (const float*)d_in[4];
  const float* a1d = (const float*)d_in[5];
  const float* We1 = (const float*)d_in[6];
  const float* ae1 = (const float*)d_in[7];
  const float* b1  = (const float*)d_in[8];
  const float* W2  = (const float*)d_in[9];
  const float* a2s = (const float*)d_in[10];
  const float* a2d = (const float*)d_in[11];
  const float* We2 = (const float*)d_in[12];
  const float* ae2 = (const float*)d_in[13];
  const float* b2  = (const float*)d_in[14];
  int N = in_sizes[0] / D;
  int E = in_sizes[1] / 2;
  const int* srcv = ei;
  const int* dstv = ei + E;
  float* out = (float*)d_out;

  char* p = (char*)d_ws;
  auto alloc = [&](size_t elems)->void*{
    void* r = (void*)p; p += ((elems*4 + 255)/256)*256; return r;
  };
  float* h    = (float*)alloc((size_t)N*D);
  float* x2   = (float*)alloc((size_t)N*D);
  float* aeE1 = (float*)alloc(E);
  float* aeE2 = (float*)alloc(E);
  float* ae1s = (float*)alloc(E);
  float* ae2s = (float*)alloc(E);
  float* as_  = (float*)alloc(N);
  float* ad_  = (float*)alloc(N);
  float* sal  = (float*)alloc(N);
  float* sum1 = (float*)alloc(N);
  float* sum2 = (float*)alloc(N);
  float* weae = (float*)alloc(256);
  int* deg    = (int*)alloc(N);
  int* cursor = (int*)alloc(N);
  int* rowp   = (int*)alloc(N+1);
  int* css    = (int*)alloc(E);
  int* bsum   = (int*)alloc(256);
  int* boff   = (int*)alloc(256);

  hipMemsetAsync(deg,    0, (size_t)N*4, stream);
  hipMemsetAsync(cursor, 0, (size_t)N*4, stream);
  hipMemsetAsync(sum1,   0, (size_t)N*4, stream);
  hipMemsetAsync(sum2,   0, (size_t)N*4, stream);

  k_weae<<<64,256,0,stream>>>(We1,ae1,We2,ae2,weae);
  k_edge<<<2048,256,0,stream>>>(ea,dstv,weae,aeE1,aeE2,sum1,sum2,deg,E);

  int nb = (N + 255)/256;
  k_scan1<<<nb,256,0,stream>>>(deg,bsum,N);
  k_scan2<<<1,256,0,stream>>>(bsum,boff,nb);
  k_scan3<<<nb,256,0,stream>>>(deg,boff,rowp,N,E);
  k_csr<<<(E+255)/256,256,0,stream>>>(srcv,dstv,rowp,cursor,css,aeE1,aeE2,ae1s,ae2s,E);

  int gemmb = (N + 31)/32;
  int wgrid = (N + 3)/4;

  // layer 1
  k_gemm<<<gemmb,256,0,stream>>>(x, W1, a1s, a1d, sum1, deg, h, as_, ad_, sal, N);
  k_aggr<<<wgrid,256,0,stream>>>(h, as_, ad_, sal, rowp, css, ae1s, b1, x2, N, 1);

  // layer 2
  k_gemm<<<gemmb,256,0,stream>>>(x2, W2, a2s, a2d, sum2, deg, h, as_, ad_, sal, N);
  k_aggr<<<wgrid,256,0,stream>>>(h, as_, ad_, sal, rowp, css, ae2s, b2, out, N, 0);
}

// Round 3
// 421.517 us; speedup vs baseline: 1.3395x; 1.2417x over previous
//
#include <hip/hip_runtime.h>
#include <cstdint>

#define D 128
#define NEG 0.2f
#define NINF (-1e30f)

__device__ __forceinline__ float wsum(float v){
#pragma unroll
  for(int m=32;m;m>>=1) v += __shfl_xor(v,m,64);
  return v;
}
__device__ __forceinline__ float wmax(float v){
#pragma unroll
  for(int m=32;m;m>>=1) v = fmaxf(v,__shfl_xor(v,m,64));
  return v;
}
__device__ __forceinline__ float hsum32(float v){
#pragma unroll
  for(int m=16;m;m>>=1) v += __shfl_xor(v,m,64);
  return v;
}
__device__ __forceinline__ float lrelu(float a){ return a>0.f ? a : NEG*a; }
__device__ __forceinline__ int   bcast_i(int v, int j){ return __builtin_amdgcn_readlane(v, j); }
__device__ __forceinline__ float bcast_f(float v, int j){
  return __int_as_float(__builtin_amdgcn_readlane(__float_as_int(v), j));
}

// ---- we_ae[l][s] = dot(We_l[s,:], ae_l) ----
__global__ __launch_bounds__(256) void k_weae(const float* __restrict__ We1, const float* __restrict__ ae1,
                                              const float* __restrict__ We2, const float* __restrict__ ae2,
                                              float* __restrict__ weae){
  int gw  = (blockIdx.x*blockDim.x + threadIdx.x) >> 6;
  int lane = threadIdx.x & 63;
  if (gw >= 256) return;
  const float* We = (gw & 128) ? We2 : We1;
  const float* ae = (gw & 128) ? ae2 : ae1;
  int row = gw & 127;
  float2 v = ((const float2*)(We + (size_t)row*D))[lane];
  float2 a = ((const float2*)ae)[lane];
  float p = wsum(v.x*a.x + v.y*a.y);
  if (!lane) weae[gw] = p;
}

// ---- one pass over edge_attr (410MB): per-edge a_e for both layers + deg + per-dst a_e sums ----
__global__ __launch_bounds__(256) void k_edge(const float* __restrict__ EA, const int* __restrict__ dstv,
                                              const float* __restrict__ weae,
                                              float2* __restrict__ aeE12,
                                              float* __restrict__ sum1, float* __restrict__ sum2,
                                              int* __restrict__ deg, int E){
  __shared__ float w1[128], w2[128];
  if (threadIdx.x < 128) w1[threadIdx.x] = weae[threadIdx.x];
  else                   w2[threadIdx.x-128] = weae[threadIdx.x];
  __syncthreads();
  int lane = threadIdx.x & 63;
  int wid  = threadIdx.x >> 6;
  float2 wa = ((const float2*)w1)[lane];
  float2 wb = ((const float2*)w2)[lane];
  for (int e = blockIdx.x*4 + wid; e < E; e += gridDim.x*4){
    float2 v = ((const float2*)(EA + (size_t)e*D))[lane];
    float s1 = wsum(v.x*wa.x + v.y*wa.y);
    float s2 = wsum(v.x*wb.x + v.y*wb.y);
    if (!lane){
      aeE12[e] = make_float2(s1, s2);
      int d = dstv[e];
      atomicAdd(deg + d, 1);
      atomicAdd(sum1 + d, s1);
      atomicAdd(sum2 + d, s2);
    }
  }
}

// ---- scan: deg -> row_ptr (exclusive) ----
__global__ __launch_bounds__(256) void k_scan1(const int* __restrict__ deg, int* __restrict__ bsum, int N){
  __shared__ int s[256];
  int i = blockIdx.x*256 + threadIdx.x;
  s[threadIdx.x] = (i < N) ? deg[i] : 0;
  __syncthreads();
#pragma unroll
  for (int st = 128; st; st >>= 1){
    if (threadIdx.x < st) s[threadIdx.x] += s[threadIdx.x + st];
    __syncthreads();
  }
  if (!threadIdx.x) bsum[blockIdx.x] = s[0];
}
__global__ __launch_bounds__(256) void k_scan2(const int* __restrict__ bsum, int* __restrict__ boff, int NB){
  __shared__ int s[256];
  int t = threadIdx.x;
  int v = (t < NB) ? bsum[t] : 0;
  s[t] = v; __syncthreads();
  for (int d = 1; d < 256; d <<= 1){
    int x = (t >= d) ? s[t-d] : 0;
    __syncthreads();
    s[t] += x;
    __syncthreads();
  }
  boff[t] = s[t] - v;
}
__global__ __launch_bounds__(256) void k_scan3(const int* __restrict__ deg, const int* __restrict__ boff,
                                               int* __restrict__ rowp, int N, int E){
  __shared__ int s[256];
  int t = threadIdx.x;
  int i = blockIdx.x*256 + t;
  int v = (i < N) ? deg[i] : 0;
  s[t] = v; __syncthreads();
  for (int d = 1; d < 256; d <<= 1){
    int x = (t >= d) ? s[t-d] : 0;
    __syncthreads();
    s[t] += x;
    __syncthreads();
  }
  if (i < N) rowp[i] = boff[blockIdx.x] + s[t] - v;
  if (i == N-1) rowp[N] = E;
}

// ---- CSR fill: dst-sorted packed records {src, ae_l1, ae_l2, 0} ----
__global__ __launch_bounds__(256) void k_csr(const int* __restrict__ srcv, const int* __restrict__ dstv,
                                             const int* __restrict__ rowp, int* __restrict__ cursor,
                                             const float2* __restrict__ aeE12,
                                             int4* __restrict__ csr, int E){
  int e = blockIdx.x*256 + threadIdx.x;
  if (e >= E) return;
  int d = dstv[e];
  int pos = rowp[d] + atomicAdd(cursor + d, 1);
  float2 ae = aeE12[e];
  int4 rec;
  rec.x = srcv[e];
  rec.y = __float_as_int(ae.x);
  rec.z = __float_as_int(ae.y);
  rec.w = 0;
  csr[pos] = rec;
}

// ---- GEMM + fused a_s/a_d/self-loop-alpha epilogue ----
__global__ __launch_bounds__(256) void k_gemm(const float* __restrict__ X, const float* __restrict__ W,
                                              const float* __restrict__ atts, const float* __restrict__ attd,
                                              const float* __restrict__ sum_ae, const int* __restrict__ deg,
                                              float* __restrict__ H, float* __restrict__ a_s,
                                              float* __restrict__ a_d, float* __restrict__ sal, int N){
  __shared__ float ws_[64][128];
  __shared__ float xs[32][132];
  int tid = threadIdx.x;
  int row0 = blockIdx.x*32;
  const float4* X4 = (const float4*)X;
#pragma unroll
  for (int i = 0; i < 4; ++i){
    int idx = tid + i*256;
    int r = idx >> 5, c = idx & 31;
    float4 v = {0.f,0.f,0.f,0.f};
    int gr = row0 + r;
    if (gr < N) v = X4[(size_t)gr*32 + c];
    *(float4*)&xs[r][c*4] = v;
  }
  int tc = tid & 31, tr = tid >> 5;
  float acc[4][4];
#pragma unroll
  for (int i=0;i<4;++i)
#pragma unroll
    for (int j=0;j<4;++j) acc[i][j]=0.f;

  const float4* W4 = (const float4*)W;
  for (int kh = 0; kh < 2; ++kh){
    __syncthreads();
#pragma unroll
    for (int i = 0; i < 8; ++i){
      int idx = tid + i*256;
      int r = idx >> 5, c = idx & 31;
      *(float4*)&ws_[r][c*4] = W4[(size_t)(kh*64 + r)*32 + c];
    }
    __syncthreads();
#pragma unroll 2
    for (int k0 = 0; k0 < 64; k0 += 4){
      float4 a0 = *(const float4*)&xs[tr     ][kh*64 + k0];
      float4 a1 = *(const float4*)&xs[tr + 8 ][kh*64 + k0];
      float4 a2 = *(const float4*)&xs[tr + 16][kh*64 + k0];
      float4 a3 = *(const float4*)&xs[tr + 24][kh*64 + k0];
      float A0[4]={a0.x,a0.y,a0.z,a0.w}, A1[4]={a1.x,a1.y,a1.z,a1.w};
      float A2[4]={a2.x,a2.y,a2.z,a2.w}, A3[4]={a3.x,a3.y,a3.z,a3.w};
#pragma unroll
      for (int kk = 0; kk < 4; ++kk){
        float4 bv = *(const float4*)&ws_[k0+kk][tc*4];
        acc[0][0]+=A0[kk]*bv.x; acc[0][1]+=A0[kk]*bv.y; acc[0][2]+=A0[kk]*bv.z; acc[0][3]+=A0[kk]*bv.w;
        acc[1][0]+=A1[kk]*bv.x; acc[1][1]+=A1[kk]*bv.y; acc[1][2]+=A1[kk]*bv.z; acc[1][3]+=A1[kk]*bv.w;
        acc[2][0]+=A2[kk]*bv.x; acc[2][1]+=A2[kk]*bv.y; acc[2][2]+=A2[kk]*bv.z; acc[2][3]+=A2[kk]*bv.w;
        acc[3][0]+=A3[kk]*bv.x; acc[3][1]+=A3[kk]*bv.y; acc[3][2]+=A3[kk]*bv.z; acc[3][3]+=A3[kk]*bv.w;
      }
    }
  }
  float4 sv = ((const float4*)atts)[tc];
  float4 dv = ((const float4*)attd)[tc];
#pragma unroll
  for (int i = 0; i < 4; ++i){
    int gr = row0 + tr + 8*i;
    float ps = acc[i][0]*sv.x + acc[i][1]*sv.y + acc[i][2]*sv.z + acc[i][3]*sv.w;
    float pd = acc[i][0]*dv.x + acc[i][1]*dv.y + acc[i][2]*dv.z + acc[i][3]*dv.w;
    ps = hsum32(ps); pd = hsum32(pd);
    if (gr < N){
      ((float4*)H)[(size_t)gr*32 + tc] = make_float4(acc[i][0],acc[i][1],acc[i][2],acc[i][3]);
      if (tc == 0){
        a_s[gr] = ps; a_d[gr] = pd;
        float la = sum_ae[gr] / fmaxf((float)deg[gr], 1.0f);
        sal[gr] = lrelu(ps + pd + la);
      }
    }
  }
}

// ---- aggregation: one wave per dst; chunked online softmax; readlane-broadcast gather loop ----
__global__ __launch_bounds__(256) void k_aggr(const float* __restrict__ H, const float* __restrict__ a_s,
                                              const float* __restrict__ a_d, const float* __restrict__ sal,
                                              const int* __restrict__ rowp, const int4* __restrict__ csr,
                                              int layer,
                                              const float* __restrict__ bias, float* __restrict__ OUT,
                                              int N, int relu){
  int wid  = (blockIdx.x*blockDim.x + threadIdx.x) >> 6;
  int lane = threadIdx.x & 63;
  if (wid >= N) return;
  int p0 = rowp[wid], p1 = rowp[wid+1];
  float ad = a_d[wid];
  float sa = sal[wid];
  float2 hv = ((const float2*)(H + (size_t)wid*D))[lane];
  // online-softmax state, seeded with the self-loop (alpha = sa)
  float m = sa, denom = 1.f, ax = hv.x, ay = hv.y;

  for (int c0 = p0; c0 < p1; c0 += 64){
    int p = c0 + lane;
    bool valid = p < p1;
    int4 rec = valid ? csr[p] : make_int4(0,0,0,0);
    int   s  = rec.x;
    float ae = __int_as_float(layer ? rec.z : rec.y);
    float alpha = valid ? lrelu(a_s[s] + ad + ae) : NINF;
    float cm = wmax(alpha);
    float mn = fmaxf(m, cm);
    float scale = __expf(m - mn);
    float ex = valid ? __expf(alpha - mn) : 0.f;
    ax *= scale; ay *= scale;
    denom = denom*scale + wsum(ex);
    m = mn;
    int cnt = p1 - c0; if (cnt > 64) cnt = 64;
    int j = 0;
    for (; j + 4 <= cnt; j += 4){
      int   s0 = bcast_i(s, j  ), s1 = bcast_i(s, j+1);
      int   s2 = bcast_i(s, j+2), s3 = bcast_i(s, j+3);
      float w0 = bcast_f(ex, j  ), w1 = bcast_f(ex, j+1);
      float w2 = bcast_f(ex, j+2), w3 = bcast_f(ex, j+3);
      float2 h0 = ((const float2*)(H + (size_t)s0*D))[lane];
      float2 h1 = ((const float2*)(H + (size_t)s1*D))[lane];
      float2 h2 = ((const float2*)(H + (size_t)s2*D))[lane];
      float2 h3 = ((const float2*)(H + (size_t)s3*D))[lane];
      ax += w0*h0.x; ay += w0*h0.y;
      ax += w1*h1.x; ay += w1*h1.y;
      ax += w2*h2.x; ay += w2*h2.y;
      ax += w3*h3.x; ay += w3*h3.y;
    }
    for (; j < cnt; ++j){
      int   sj = bcast_i(s, j);
      float wj = bcast_f(ex, j);
      float2 hj = ((const float2*)(H + (size_t)sj*D))[lane];
      ax += wj*hj.x; ay += wj*hj.y;
    }
  }
  float2 bv = ((const float2*)bias)[lane];
  float inv = 1.0f/denom;
  float ox = ax*inv + bv.x, oy = ay*inv + bv.y;
  if (relu){ ox = fmaxf(ox, 0.f); oy = fmaxf(oy, 0.f); }
  ((float2*)(OUT + (size_t)wid*D))[lane] = make_float2(ox, oy);
}

extern "C" void kernel_launch(void* const* d_in, const int* in_sizes, int n_in,
                              void* d_out, int out_size, void* d_ws, size_t ws_size,
                              hipStream_t stream){
  (void)n_in; (void)out_size; (void)ws_size;
  const float* x   = (const float*)d_in[0];
  const int*   ei  = (const int*)d_in[1];
  const float* ea  = (const float*)d_in[2];
  const float* W1  = (const float*)d_in[3];
  const float* a1s = (const float*)d_in[4];
  const float* a1d = (const float*)d_in[5];
  const float* We1 = (const float*)d_in[6];
  const float* ae1 = (const float*)d_in[7];
  const float* b1  = (const float*)d_in[8];
  const float* W2  = (const float*)d_in[9];
  const float* a2s = (const float*)d_in[10];
  const float* a2d = (const float*)d_in[11];
  const float* We2 = (const float*)d_in[12];
  const float* ae2 = (const float*)d_in[13];
  const float* b2  = (const float*)d_in[14];
  int N = in_sizes[0] / D;
  int E = in_sizes[1] / 2;
  const int* srcv = ei;
  const int* dstv = ei + E;
  float* out = (float*)d_out;

  char* p = (char*)d_ws;
  auto alloc = [&](size_t elems)->void*{
    void* r = (void*)p; p += ((elems*4 + 255)/256)*256; return r;
  };
  // contiguous zero region first: deg, cursor, sum1, sum2
  int* deg    = (int*)alloc(N);
  int* cursor = (int*)alloc(N);
  float* sum1 = (float*)alloc(N);
  float* sum2 = (float*)alloc(N);
  char* zero_end = p;
  float* h    = (float*)alloc((size_t)N*D);
  float* x2   = (float*)alloc((size_t)N*D);
  float* aeE12= (float*)alloc((size_t)E*2);
  int4* csr   = (int4*)alloc((size_t)E*4);
  float* as_  = (float*)alloc(N);
  float* ad_  = (float*)alloc(N);
  float* sal  = (float*)alloc(N);
  float* weae = (float*)alloc(256);
  int* rowp   = (int*)alloc(N+1);
  int* bsum   = (int*)alloc(256);
  int* boff   = (int*)alloc(256);

  hipMemsetAsync(deg, 0, (size_t)(zero_end - (char*)deg), stream);

  k_weae<<<64,256,0,stream>>>(We1,ae1,We2,ae2,weae);
  k_edge<<<2048,256,0,stream>>>(ea,dstv,weae,(float2*)aeE12,sum1,sum2,deg,E);

  int nb = (N + 255)/256;
  k_scan1<<<nb,256,0,stream>>>(deg,bsum,N);
  k_scan2<<<1,256,0,stream>>>(bsum,boff,nb);
  k_scan3<<<nb,256,0,stream>>>(deg,boff,rowp,N,E);
  k_csr<<<(E+255)/256,256,0,stream>>>(srcv,dstv,rowp,cursor,(const float2*)aeE12,csr,E);

  int gemmb = (N + 31)/32;
  int wgrid = (N + 3)/4;

  // layer 1
  k_gemm<<<gemmb,256,0,stream>>>(x, W1, a1s, a1d, sum1, deg, h, as_, ad_, sal, N);
  k_aggr<<<wgrid,256,0,stream>>>(h, as_, ad_, sal, rowp, csr, 0, b1, x2, N, 1);

  // layer 2
  k_gemm<<<gemmb,256,0,stream>>>(x2, W2, a2s, a2d, sum2, deg, h, as_, ad_, sal, N);
  k_aggr<<<wgrid,256,0,stream>>>(h, as_, ad_, sal, rowp, csr, 1, b2, out, N, 0);
}

// Round 5
// 419.985 us; speedup vs baseline: 1.3443x; 1.0036x over previous
//
#include <hip/hip_runtime.h>
#include <cstdint>

#define D 128
#define NEG 0.2f

__device__ __forceinline__ float wsum(float v){
#pragma unroll
  for(int m=32;m;m>>=1) v += __shfl_xor(v,m,64);
  return v;
}
__device__ __forceinline__ float hsum32(float v){
#pragma unroll
  for(int m=16;m;m>>=1) v += __shfl_xor(v,m,64);
  return v;
}
__device__ __forceinline__ float lrelu(float a){ return a>0.f ? a : NEG*a; }

// ---- we_ae[l][s] = dot(We_l[s,:], ae_l) ----
__global__ __launch_bounds__(256) void k_weae(const float* __restrict__ We1, const float* __restrict__ ae1,
                                              const float* __restrict__ We2, const float* __restrict__ ae2,
                                              float* __restrict__ weae){
  int gw  = (blockIdx.x*blockDim.x + threadIdx.x) >> 6;
  int lane = threadIdx.x & 63;
  if (gw >= 256) return;
  const float* We = (gw & 128) ? We2 : We1;
  const float* ae = (gw & 128) ? ae2 : ae1;
  int row = gw & 127;
  float2 v = ((const float2*)(We + (size_t)row*D))[lane];
  float2 a = ((const float2*)ae)[lane];
  float p = wsum(v.x*a.x + v.y*a.y);
  if (!lane) weae[gw] = p;
}

// ---- one pass over edge_attr (410MB): per-edge a_e for both layers + deg + per-dst a_e sums ----
__global__ __launch_bounds__(256) void k_edge(const float* __restrict__ EA, const int* __restrict__ dstv,
                                              const float* __restrict__ weae,
                                              float2* __restrict__ aeE12,
                                              float* __restrict__ sum1, float* __restrict__ sum2,
                                              int* __restrict__ deg, int E){
  __shared__ float w1[128], w2[128];
  if (threadIdx.x < 128) w1[threadIdx.x] = weae[threadIdx.x];
  else                   w2[threadIdx.x-128] = weae[threadIdx.x];
  __syncthreads();
  int lane = threadIdx.x & 63;
  int wid  = threadIdx.x >> 6;
  float2 wa = ((const float2*)w1)[lane];
  float2 wb = ((const float2*)w2)[lane];
  for (int e = blockIdx.x*4 + wid; e < E; e += gridDim.x*4){
    float2 v = ((const float2*)(EA + (size_t)e*D))[lane];
    float s1 = wsum(v.x*wa.x + v.y*wa.y);
    float s2 = wsum(v.x*wb.x + v.y*wb.y);
    if (!lane){
      aeE12[e] = make_float2(s1, s2);
      int d = dstv[e];
      atomicAdd(deg + d, 1);
      atomicAdd(sum1 + d, s1);
      atomicAdd(sum2 + d, s2);
    }
  }
}

// ---- scan: deg -> row_ptr (exclusive) ----
__global__ __launch_bounds__(256) void k_scan1(const int* __restrict__ deg, int* __restrict__ bsum, int N){
  __shared__ int s[256];
  int i = blockIdx.x*256 + threadIdx.x;
  s[threadIdx.x] = (i < N) ? deg[i] : 0;
  __syncthreads();
#pragma unroll
  for (int st = 128; st; st >>= 1){
    if (threadIdx.x < st) s[threadIdx.x] += s[threadIdx.x + st];
    __syncthreads();
  }
  if (!threadIdx.x) bsum[blockIdx.x] = s[0];
}
__global__ __launch_bounds__(256) void k_scan2(const int* __restrict__ bsum, int* __restrict__ boff, int NB){
  __shared__ int s[256];
  int t = threadIdx.x;
  int v = (t < NB) ? bsum[t] : 0;
  s[t] = v; __syncthreads();
  for (int d = 1; d < 256; d <<= 1){
    int x = (t >= d) ? s[t-d] : 0;
    __syncthreads();
    s[t] += x;
    __syncthreads();
  }
  boff[t] = s[t] - v;
}
__global__ __launch_bounds__(256) void k_scan3(const int* __restrict__ deg, const int* __restrict__ boff,
                                               int* __restrict__ rowp, int N, int E){
  __shared__ int s[256];
  int t = threadIdx.x;
  int i = blockIdx.x*256 + t;
  int v = (i < N) ? deg[i] : 0;
  s[t] = v; __syncthreads();
  for (int d = 1; d < 256; d <<= 1){
    int x = (t >= d) ? s[t-d] : 0;
    __syncthreads();
    s[t] += x;
    __syncthreads();
  }
  if (i < N) rowp[i] = boff[blockIdx.x] + s[t] - v;
  if (i == N-1) rowp[N] = E;
}

// ---- CSR fill: dst-sorted packed records {src, ae_l1, ae_l2, 0} ----
__global__ __launch_bounds__(256) void k_csr(const int* __restrict__ srcv, const int* __restrict__ dstv,
                                             const int* __restrict__ rowp, int* __restrict__ cursor,
                                             const float2* __restrict__ aeE12,
                                             int4* __restrict__ csr, int E){
  int e = blockIdx.x*256 + threadIdx.x;
  if (e >= E) return;
  int d = dstv[e];
  int pos = rowp[d] + atomicAdd(cursor + d, 1);
  float2 ae = aeE12[e];
  int4 rec;
  rec.x = srcv[e];
  rec.y = __float_as_int(ae.x);
  rec.z = __float_as_int(ae.y);
  rec.w = 0;
  csr[pos] = rec;
}

// ---- GEMM + fused a_s/a_d/self-loop-alpha epilogue ----
__global__ __launch_bounds__(256) void k_gemm(const float* __restrict__ X, const float* __restrict__ W,
                                              const float* __restrict__ atts, const float* __restrict__ attd,
                                              const float* __restrict__ sum_ae, const int* __restrict__ deg,
                                              float* __restrict__ H, float* __restrict__ a_s,
                                              float* __restrict__ a_d, float* __restrict__ sal, int N){
  __shared__ float ws_[64][128];
  __shared__ float xs[32][132];
  int tid = threadIdx.x;
  int row0 = blockIdx.x*32;
  const float4* X4 = (const float4*)X;
#pragma unroll
  for (int i = 0; i < 4; ++i){
    int idx = tid + i*256;
    int r = idx >> 5, c = idx & 31;
    float4 v = {0.f,0.f,0.f,0.f};
    int gr = row0 + r;
    if (gr < N) v = X4[(size_t)gr*32 + c];
    *(float4*)&xs[r][c*4] = v;
  }
  int tc = tid & 31, tr = tid >> 5;
  float acc[4][4];
#pragma unroll
  for (int i=0;i<4;++i)
#pragma unroll
    for (int j=0;j<4;++j) acc[i][j]=0.f;

  const float4* W4 = (const float4*)W;
  for (int kh = 0; kh < 2; ++kh){
    __syncthreads();
#pragma unroll
    for (int i = 0; i < 8; ++i){
      int idx = tid + i*256;
      int r = idx >> 5, c = idx & 31;
      *(float4*)&ws_[r][c*4] = W4[(size_t)(kh*64 + r)*32 + c];
    }
    __syncthreads();
#pragma unroll 2
    for (int k0 = 0; k0 < 64; k0 += 4){
      float4 a0 = *(const float4*)&xs[tr     ][kh*64 + k0];
      float4 a1 = *(const float4*)&xs[tr + 8 ][kh*64 + k0];
      float4 a2 = *(const float4*)&xs[tr + 16][kh*64 + k0];
      float4 a3 = *(const float4*)&xs[tr + 24][kh*64 + k0];
      float A0[4]={a0.x,a0.y,a0.z,a0.w}, A1[4]={a1.x,a1.y,a1.z,a1.w};
      float A2[4]={a2.x,a2.y,a2.z,a2.w}, A3[4]={a3.x,a3.y,a3.z,a3.w};
#pragma unroll
      for (int kk = 0; kk < 4; ++kk){
        float4 bv = *(const float4*)&ws_[k0+kk][tc*4];
        acc[0][0]+=A0[kk]*bv.x; acc[0][1]+=A0[kk]*bv.y; acc[0][2]+=A0[kk]*bv.z; acc[0][3]+=A0[kk]*bv.w;
        acc[1][0]+=A1[kk]*bv.x; acc[1][1]+=A1[kk]*bv.y; acc[1][2]+=A1[kk]*bv.z; acc[1][3]+=A1[kk]*bv.w;
        acc[2][0]+=A2[kk]*bv.x; acc[2][1]+=A2[kk]*bv.y; acc[2][2]+=A2[kk]*bv.z; acc[2][3]+=A2[kk]*bv.w;
        acc[3][0]+=A3[kk]*bv.x; acc[3][1]+=A3[kk]*bv.y; acc[3][2]+=A3[kk]*bv.z; acc[3][3]+=A3[kk]*bv.w;
      }
    }
  }
  float4 sv = ((const float4*)atts)[tc];
  float4 dv = ((const float4*)attd)[tc];
#pragma unroll
  for (int i = 0; i < 4; ++i){
    int gr = row0 + tr + 8*i;
    float ps = acc[i][0]*sv.x + acc[i][1]*sv.y + acc[i][2]*sv.z + acc[i][3]*sv.w;
    float pd = acc[i][0]*dv.x + acc[i][1]*dv.y + acc[i][2]*dv.z + acc[i][3]*dv.w;
    ps = hsum32(ps); pd = hsum32(pd);
    if (gr < N){
      ((float4*)H)[(size_t)gr*32 + tc] = make_float4(acc[i][0],acc[i][1],acc[i][2],acc[i][3]);
      if (tc == 0){
        a_s[gr] = ps; a_d[gr] = pd;
        float la = sum_ae[gr] / fmaxf((float)deg[gr], 1.0f);
        sal[gr] = lrelu(ps + pd + la);
      }
    }
  }
}

// ---- aggregation v4: one wave per dst; no max-subtraction; half-wave (32-lane) rows.
//      ALL loop bounds wave-uniform so __shfl never sources an inactive lane. ----
__global__ __launch_bounds__(256) void k_aggr(const float* __restrict__ H, const float* __restrict__ a_s,
                                              const float* __restrict__ a_d, const float* __restrict__ sal,
                                              const int* __restrict__ rowp, const int4* __restrict__ csr,
                                              int layer,
                                              const float* __restrict__ bias, float* __restrict__ OUT,
                                              int N, int relu){
  int wid  = (blockIdx.x*blockDim.x + threadIdx.x) >> 6;
  int lane = threadIdx.x & 63;
  if (wid >= N) return;
  int p0 = rowp[wid], p1 = rowp[wid+1];
  float ad = a_d[wid];
  int l32 = lane & 31;
  int hw  = lane >> 5;
  float ex_self = __expf(sal[wid]);
  float denom = ex_self;
  float4 acc = {0.f,0.f,0.f,0.f};
  if (!hw){
    float4 hs = *(const float4*)(H + wid*D + l32*4);
    acc.x = ex_self*hs.x; acc.y = ex_self*hs.y; acc.z = ex_self*hs.z; acc.w = ex_self*hs.w;
  }
  for (int c0 = p0; c0 < p1; c0 += 64){
    int p = c0 + lane;
    bool valid = p < p1;
    int4 rec = valid ? csr[p] : make_int4(0,0,0,0);
    int   s  = rec.x;
    float ae = __int_as_float(layer ? rec.z : rec.y);
    float ex = valid ? __expf(lrelu(a_s[s] + ad + ae)) : 0.f;
    denom += wsum(ex);
    int cnt = p1 - c0; if (cnt > 64) cnt = 64;   // wave-uniform
    int i8 = 0;
    // full blocks of 8: uniform bound -> all 64 lanes active at every __shfl
    for (; i8 + 8 <= cnt; i8 += 8){
      int j = i8 + hw;
      int   s0 = __shfl(s, j  ), s1 = __shfl(s, j+2);
      int   s2 = __shfl(s, j+4), s3 = __shfl(s, j+6);
      float w0 = __shfl(ex, j  ), w1 = __shfl(ex, j+2);
      float w2 = __shfl(ex, j+4), w3 = __shfl(ex, j+6);
      float4 h0 = *(const float4*)(H + s0*D + l32*4);
      float4 h1 = *(const float4*)(H + s1*D + l32*4);
      float4 h2 = *(const float4*)(H + s2*D + l32*4);
      float4 h3 = *(const float4*)(H + s3*D + l32*4);
      acc.x += w0*h0.x + w1*h1.x + w2*h2.x + w3*h3.x;
      acc.y += w0*h0.y + w1*h1.y + w2*h2.y + w3*h3.y;
      acc.z += w0*h0.z + w1*h1.z + w2*h2.z + w3*h3.z;
      acc.w += w0*h0.w + w1*h1.w + w2*h2.w + w3*h3.w;
    }
    // tail: uniform bound; out-of-range lanes clamp shfl index and zero the weight
    for (int j0 = i8; j0 < cnt; j0 += 2){
      int j  = j0 + hw;
      int jc = (j < cnt) ? j : 0;
      int   sj = __shfl(s, jc);
      float wj = __shfl(ex, jc);
      if (j >= cnt) wj = 0.f;
      float4 hj = *(const float4*)(H + sj*D + l32*4);
      acc.x += wj*hj.x; acc.y += wj*hj.y; acc.z += wj*hj.z; acc.w += wj*hj.w;
    }
  }
  // combine the two halves
  acc.x += __shfl_xor(acc.x, 32);
  acc.y += __shfl_xor(acc.y, 32);
  acc.z += __shfl_xor(acc.z, 32);
  acc.w += __shfl_xor(acc.w, 32);
  if (!hw){
    float4 bv = *(const float4*)(bias + l32*4);
    float inv = 1.0f/denom;
    float ox = acc.x*inv + bv.x, oy = acc.y*inv + bv.y;
    float oz = acc.z*inv + bv.z, ow = acc.w*inv + bv.w;
    if (relu){ ox=fmaxf(ox,0.f); oy=fmaxf(oy,0.f); oz=fmaxf(oz,0.f); ow=fmaxf(ow,0.f); }
    *(float4*)(OUT + wid*D + l32*4) = make_float4(ox,oy,oz,ow);
  }
}

extern "C" void kernel_launch(void* const* d_in, const int* in_sizes, int n_in,
                              void* d_out, int out_size, void* d_ws, size_t ws_size,
                              hipStream_t stream){
  (void)n_in; (void)out_size; (void)ws_size;
  const float* x   = (const float*)d_in[0];
  const int*   ei  = (const int*)d_in[1];
  const float* ea  = (const float*)d_in[2];
  const float* W1  = (const float*)d_in[3];
  const float* a1s = (const float*)d_in[4];
  const float* a1d = (const float*)d_in[5];
  const float* We1 = (const float*)d_in[6];
  const float* ae1 = (const float*)d_in[7];
  const float* b1  = (const float*)d_in[8];
  const float* W2  = (const float*)d_in[9];
  const float* a2s = (const float*)d_in[10];
  const float* a2d = (const float*)d_in[11];
  const float* We2 = (const float*)d_in[12];
  const float* ae2 = (const float*)d_in[13];
  const float* b2  = (const float*)d_in[14];
  int N = in_sizes[0] / D;
  int E = in_sizes[1] / 2;
  const int* srcv = ei;
  const int* dstv = ei + E;
  float* out = (float*)d_out;

  char* p = (char*)d_ws;
  auto alloc = [&](size_t elems)->void*{
    void* r = (void*)p; p += ((elems*4 + 255)/256)*256; return r;
  };
  int* deg    = (int*)alloc(N);
  int* cursor = (int*)alloc(N);
  float* sum1 = (float*)alloc(N);
  float* sum2 = (float*)alloc(N);
  char* zero_end = p;
  float* h    = (float*)alloc((size_t)N*D);
  float* x2   = (float*)alloc((size_t)N*D);
  float* aeE12= (float*)alloc((size_t)E*2);
  int4* csr   = (int4*)alloc((size_t)E*4);
  float* as_  = (float*)alloc(N);
  float* ad_  = (float*)alloc(N);
  float* sal  = (float*)alloc(N);
  float* weae = (float*)alloc(256);
  int* rowp   = (int*)alloc(N+1);
  int* bsum   = (int*)alloc(256);
  int* boff   = (int*)alloc(256);

  hipMemsetAsync(deg, 0, (size_t)(zero_end - (char*)deg), stream);

  k_weae<<<64,256,0,stream>>>(We1,ae1,We2,ae2,weae);
  k_edge<<<2048,256,0,stream>>>(ea,dstv,weae,(float2*)aeE12,sum1,sum2,deg,E);

  int nb = (N + 255)/256;
  k_scan1<<<nb,256,0,stream>>>(deg,bsum,N);
  k_scan2<<<1,256,0,stream>>>(bsum,boff,nb);
  k_scan3<<<nb,256,0,stream>>>(deg,boff,rowp,N,E);
  k_csr<<<(E+255)/256,256,0,stream>>>(srcv,dstv,rowp,cursor,(const float2*)aeE12,csr,E);

  int gemmb = (N + 31)/32;
  int wgrid = (N + 3)/4;

  // layer 1
  k_gemm<<<gemmb,256,0,stream>>>(x, W1, a1s, a1d, sum1, deg, h, as_, ad_, sal, N);
  k_aggr<<<wgrid,256,0,stream>>>(h, as_, ad_, sal, rowp, csr, 0, b1, x2, N, 1);

  // layer 2
  k_gemm<<<gemmb,256,0,stream>>>(x2, W2, a2s, a2d, sum2, deg, h, as_, ad_, sal, N);
  k_aggr<<<wgrid,256,0,stream>>>(h, as_, ad_, sal, rowp, csr, 1, b2, out, N, 0);
}

// Round 6
// 355.881 us; speedup vs baseline: 1.5865x; 1.1801x over previous
//
#include <hip/hip_runtime.h>
#include <cstdint>

#define D 128
#define NEG 0.2f

typedef __attribute__((ext_vector_type(8))) short bf16x8;
typedef __attribute__((ext_vector_type(4))) float f32x4;

__device__ __forceinline__ float wsum(float v){
#pragma unroll
  for(int m=32;m;m>>=1) v += __shfl_xor(v,m,64);
  return v;
}
__device__ __forceinline__ float lrelu(float a){ return a>0.f ? a : NEG*a; }
__device__ __forceinline__ unsigned short f2bf(float f){
  unsigned int u = __float_as_uint(f);
  u += 0x7fffu + ((u>>16)&1u);
  return (unsigned short)(u>>16);
}
__device__ __forceinline__ float bf2f(unsigned short s){
  return __uint_as_float(((unsigned int)s)<<16);
}

// ---- we_ae[l][s] = dot(We_l[s,:], ae_l) ----
__global__ __launch_bounds__(256) void k_weae(const float* __restrict__ We1, const float* __restrict__ ae1,
                                              const float* __restrict__ We2, const float* __restrict__ ae2,
                                              float* __restrict__ weae){
  int gw  = (blockIdx.x*blockDim.x + threadIdx.x) >> 6;
  int lane = threadIdx.x & 63;
  if (gw >= 256) return;
  const float* We = (gw & 128) ? We2 : We1;
  const float* ae = (gw & 128) ? ae2 : ae1;
  int row = gw & 127;
  float2 v = ((const float2*)(We + (size_t)row*D))[lane];
  float2 a = ((const float2*)ae)[lane];
  float p = wsum(v.x*a.x + v.y*a.y);
  if (!lane) weae[gw] = p;
}

// ---- x (fp32) -> xb (bf16), 8 elems/thread ----
__global__ __launch_bounds__(256) void k_cvt(const float* __restrict__ X, ushort* __restrict__ Xb, int n8){
  int i = blockIdx.x*256 + threadIdx.x;
  if (i >= n8) return;
  float4 a = ((const float4*)X)[i*2];
  float4 b = ((const float4*)X)[i*2+1];
  uint4 o;
  o.x = (unsigned)f2bf(a.x) | ((unsigned)f2bf(a.y)<<16);
  o.y = (unsigned)f2bf(a.z) | ((unsigned)f2bf(a.w)<<16);
  o.z = (unsigned)f2bf(b.x) | ((unsigned)f2bf(b.y)<<16);
  o.w = (unsigned)f2bf(b.z) | ((unsigned)f2bf(b.w)<<16);
  ((uint4*)Xb)[i] = o;
}

// ---- W[k][c] fp32 -> Wtb[layer][c][k] bf16 (transpose + cvt) ----
__global__ __launch_bounds__(256) void k_wt(const float* __restrict__ W1, const float* __restrict__ W2,
                                            ushort* __restrict__ Wtb){
  __shared__ ushort lds[16][128];
  int b = blockIdx.x;          // 0..15
  int layer = b >> 3;
  int kb = (b & 7) * 16;
  const float* W = layer ? W2 : W1;
  int t = threadIdx.x;
#pragma unroll
  for (int p = 0; p < 8; ++p){
    int idx = t + p*256;
    int kl = idx >> 7, c = idx & 127;
    lds[kl][c] = f2bf(W[(size_t)(kb+kl)*128 + c]);
  }
  __syncthreads();
  int c = t >> 1, kc = (t & 1) * 8;
  ushort tmp[8];
#pragma unroll
  for (int m = 0; m < 8; ++m) tmp[m] = lds[kc+m][c];
  *(uint4*)&Wtb[(size_t)layer*16384 + (size_t)c*128 + kb + kc] = *(uint4*)tmp;
}

// ---- one pass over edge_attr (410MB) ----
__global__ __launch_bounds__(256) void k_edge(const float* __restrict__ EA, const int* __restrict__ dstv,
                                              const float* __restrict__ weae,
                                              float2* __restrict__ aeE12,
                                              float* __restrict__ sum1, float* __restrict__ sum2,
                                              int* __restrict__ deg, int E){
  __shared__ float w1[128], w2[128];
  if (threadIdx.x < 128) w1[threadIdx.x] = weae[threadIdx.x];
  else                   w2[threadIdx.x-128] = weae[threadIdx.x];
  __syncthreads();
  int lane = threadIdx.x & 63;
  int wid  = threadIdx.x >> 6;
  float2 wa = ((const float2*)w1)[lane];
  float2 wb = ((const float2*)w2)[lane];
  for (int e = blockIdx.x*4 + wid; e < E; e += gridDim.x*4){
    float2 v = ((const float2*)(EA + (size_t)e*D))[lane];
    float s1 = wsum(v.x*wa.x + v.y*wa.y);
    float s2 = wsum(v.x*wb.x + v.y*wb.y);
    if (!lane){
      aeE12[e] = make_float2(s1, s2);
      int d = dstv[e];
      atomicAdd(deg + d, 1);
      atomicAdd(sum1 + d, s1);
      atomicAdd(sum2 + d, s2);
    }
  }
}

// ---- scan: deg -> row_ptr (exclusive) ----
__global__ __launch_bounds__(256) void k_scan1(const int* __restrict__ deg, int* __restrict__ bsum, int N){
  __shared__ int s[256];
  int i = blockIdx.x*256 + threadIdx.x;
  s[threadIdx.x] = (i < N) ? deg[i] : 0;
  __syncthreads();
#pragma unroll
  for (int st = 128; st; st >>= 1){
    if (threadIdx.x < st) s[threadIdx.x] += s[threadIdx.x + st];
    __syncthreads();
  }
  if (!threadIdx.x) bsum[blockIdx.x] = s[0];
}
__global__ __launch_bounds__(256) void k_scan2(const int* __restrict__ bsum, int* __restrict__ boff, int NB){
  __shared__ int s[256];
  int t = threadIdx.x;
  int v = (t < NB) ? bsum[t] : 0;
  s[t] = v; __syncthreads();
  for (int d = 1; d < 256; d <<= 1){
    int x = (t >= d) ? s[t-d] : 0;
    __syncthreads();
    s[t] += x;
    __syncthreads();
  }
  boff[t] = s[t] - v;
}
__global__ __launch_bounds__(256) void k_scan3(const int* __restrict__ deg, const int* __restrict__ boff,
                                               int* __restrict__ rowp, int N, int E){
  __shared__ int s[256];
  int t = threadIdx.x;
  int i = blockIdx.x*256 + t;
  int v = (i < N) ? deg[i] : 0;
  s[t] = v; __syncthreads();
  for (int d = 1; d < 256; d <<= 1){
    int x = (t >= d) ? s[t-d] : 0;
    __syncthreads();
    s[t] += x;
    __syncthreads();
  }
  if (i < N) rowp[i] = boff[blockIdx.x] + s[t] - v;
  if (i == N-1) rowp[N] = E;
}

// ---- CSR fill: dst-sorted packed records {src, ae_l1, ae_l2, 0} ----
__global__ __launch_bounds__(256) void k_csr(const int* __restrict__ srcv, const int* __restrict__ dstv,
                                             const int* __restrict__ rowp, int* __restrict__ cursor,
                                             const float2* __restrict__ aeE12,
                                             int4* __restrict__ csr, int E){
  int e = blockIdx.x*256 + threadIdx.x;
  if (e >= E) return;
  int d = dstv[e];
  int pos = rowp[d] + atomicAdd(cursor + d, 1);
  float2 ae = aeE12[e];
  int4 rec;
  rec.x = srcv[e];
  rec.y = __float_as_int(ae.x);
  rec.z = __float_as_int(ae.y);
  rec.w = 0;
  csr[pos] = rec;
}

// ---- MFMA GEMM: H = Xb @ W (bf16 in, fp32 out) + fused a_s/a_d/sal epilogue + Hb bf16 out ----
// block: 256 thr = 4 waves, 64 rows; wave w: rows blk*64 + w*16, all 128 cols.
__global__ __launch_bounds__(256) void k_gemm(const ushort* __restrict__ Xb, const ushort* __restrict__ Wtb,
                                              const float* __restrict__ atts, const float* __restrict__ attd,
                                              const float* __restrict__ sum_ae, const int* __restrict__ deg,
                                              float* __restrict__ H, ushort* __restrict__ Hb,
                                              float* __restrict__ a_s, float* __restrict__ a_d,
                                              float* __restrict__ sal, int N){
  __shared__ ushort xsb[64*136];    // A tile [row][k], k padded to 136
  __shared__ ushort wsb[128*136];   // B tile [col][k] (W^T), k padded to 136
  int tid = threadIdx.x;
  int rowbase = blockIdx.x*64;
  // stage A: 64 rows x 16 chunks of 8 ushort (16B)
#pragma unroll
  for (int i = 0; i < 4; ++i){
    int idx = tid + i*256;
    int r = idx >> 4, ch = idx & 15;
    int gr = rowbase + r;
    int grc = (gr < N) ? gr : 0;
    *(uint4*)&xsb[r*136 + ch*8] = *(const uint4*)&Xb[(size_t)grc*128 + ch*8];
  }
  // stage B: 128 cols x 16 chunks
#pragma unroll
  for (int i = 0; i < 8; ++i){
    int idx = tid + i*256;
    int c = idx >> 4, ch = idx & 15;
    *(uint4*)&wsb[c*136 + ch*8] = *(const uint4*)&Wtb[(size_t)c*128 + ch*8];
  }
  __syncthreads();

  int lane = tid & 63;
  int w    = tid >> 6;
  int l15  = lane & 15;
  int lg   = lane >> 4;          // 0..3
  int r0   = w*16;

  f32x4 acc[8];
#pragma unroll
  for (int ct = 0; ct < 8; ++ct) acc[ct] = (f32x4){0.f,0.f,0.f,0.f};

#pragma unroll
  for (int ks = 0; ks < 4; ++ks){
    bf16x8 af = *(const bf16x8*)&xsb[(r0 + l15)*136 + ks*32 + lg*8];
#pragma unroll
    for (int ct = 0; ct < 8; ++ct){
      bf16x8 bfr = *(const bf16x8*)&wsb[(ct*16 + l15)*136 + ks*32 + lg*8];
      acc[ct] = __builtin_amdgcn_mfma_f32_16x16x32_bf16(af, bfr, acc[ct], 0, 0, 0);
    }
  }

  // epilogue: a_s/a_d partial dots + reduce over the 16 lanes of each row-group
  float attsv[8], attdv[8];
#pragma unroll
  for (int ct = 0; ct < 8; ++ct){
    attsv[ct] = atts[ct*16 + l15];
    attdv[ct] = attd[ct*16 + l15];
  }
  float ps[4] = {0,0,0,0}, pd[4] = {0,0,0,0};
#pragma unroll
  for (int ct = 0; ct < 8; ++ct)
#pragma unroll
    for (int j = 0; j < 4; ++j){
      ps[j] += acc[ct][j]*attsv[ct];
      pd[j] += acc[ct][j]*attdv[ct];
    }
#pragma unroll
  for (int m = 1; m <= 8; m <<= 1)
#pragma unroll
    for (int j = 0; j < 4; ++j){
      ps[j] += __shfl_xor(ps[j], m, 64);
      pd[j] += __shfl_xor(pd[j], m, 64);
    }
  // stores
#pragma unroll
  for (int j = 0; j < 4; ++j){
    int gr = rowbase + r0 + lg*4 + j;
    if (gr < N){
#pragma unroll
      for (int ct = 0; ct < 8; ++ct){
        int col = ct*16 + l15;
        float v = acc[ct][j];
        H [(size_t)gr*128 + col] = v;
        Hb[(size_t)gr*128 + col] = f2bf(v);
      }
      if (l15 == 0){
        a_s[gr] = ps[j];
        a_d[gr] = pd[j];
        float la = sum_ae[gr] / fmaxf((float)deg[gr], 1.0f);
        sal[gr] = lrelu(ps[j] + pd[j] + la);
      }
    }
  }
}

// ---- aggregation: one wave per dst; bf16 gather (256B/edge); uniform-shfl loops ----
__global__ __launch_bounds__(256) void k_aggr(const float* __restrict__ H, const ushort* __restrict__ Hb,
                                              const float* __restrict__ a_s, const float* __restrict__ a_d,
                                              const float* __restrict__ sal,
                                              const int* __restrict__ rowp, const int4* __restrict__ csr,
                                              int layer,
                                              const float* __restrict__ bias,
                                              float* __restrict__ OUTF, ushort* __restrict__ OUTB, int N){
  int wid  = (blockIdx.x*blockDim.x + threadIdx.x) >> 6;
  int lane = threadIdx.x & 63;
  if (wid >= N) return;
  int p0 = rowp[wid], p1 = rowp[wid+1];
  float ad = a_d[wid];
  int l32 = lane & 31;
  int hw  = lane >> 5;
  float ex_self = __expf(sal[wid]);
  float denom = ex_self;
  float4 acc = {0.f,0.f,0.f,0.f};
  if (!hw){
    float4 hs = *(const float4*)(H + (size_t)wid*D + l32*4);
    acc.x = ex_self*hs.x; acc.y = ex_self*hs.y; acc.z = ex_self*hs.z; acc.w = ex_self*hs.w;
  }
  for (int c0 = p0; c0 < p1; c0 += 64){
    int p = c0 + lane;
    bool valid = p < p1;
    int4 rec = valid ? csr[p] : make_int4(0,0,0,0);
    int   s  = rec.x;
    float ae = __int_as_float(layer ? rec.z : rec.y);
    float ex = valid ? __expf(lrelu(a_s[s] + ad + ae)) : 0.f;
    denom += wsum(ex);
    int cnt = p1 - c0; if (cnt > 64) cnt = 64;   // wave-uniform
    int i8 = 0;
    for (; i8 + 8 <= cnt; i8 += 8){
      int j = i8 + hw;
      int   s0 = __shfl(s, j  ), s1 = __shfl(s, j+2);
      int   s2 = __shfl(s, j+4), s3 = __shfl(s, j+6);
      float w0 = __shfl(ex, j  ), w1 = __shfl(ex, j+2);
      float w2 = __shfl(ex, j+4), w3 = __shfl(ex, j+6);
      ushort4 u0 = *(const ushort4*)(Hb + (size_t)s0*D + l32*4);
      ushort4 u1 = *(const ushort4*)(Hb + (size_t)s1*D + l32*4);
      ushort4 u2 = *(const ushort4*)(Hb + (size_t)s2*D + l32*4);
      ushort4 u3 = *(const ushort4*)(Hb + (size_t)s3*D + l32*4);
      acc.x += w0*bf2f(u0.x) + w1*bf2f(u1.x) + w2*bf2f(u2.x) + w3*bf2f(u3.x);
      acc.y += w0*bf2f(u0.y) + w1*bf2f(u1.y) + w2*bf2f(u2.y) + w3*bf2f(u3.y);
      acc.z += w0*bf2f(u0.z) + w1*bf2f(u1.z) + w2*bf2f(u2.z) + w3*bf2f(u3.z);
      acc.w += w0*bf2f(u0.w) + w1*bf2f(u1.w) + w2*bf2f(u2.w) + w3*bf2f(u3.w);
    }
    for (int j0 = i8; j0 < cnt; j0 += 2){
      int j  = j0 + hw;
      int jc = (j < cnt) ? j : 0;
      int   sj = __shfl(s, jc);
      float wj = __shfl(ex, jc);
      if (j >= cnt) wj = 0.f;
      ushort4 uj = *(const ushort4*)(Hb + (size_t)sj*D + l32*4);
      acc.x += wj*bf2f(uj.x); acc.y += wj*bf2f(uj.y);
      acc.z += wj*bf2f(uj.z); acc.w += wj*bf2f(uj.w);
    }
  }
  acc.x += __shfl_xor(acc.x, 32);
  acc.y += __shfl_xor(acc.y, 32);
  acc.z += __shfl_xor(acc.z, 32);
  acc.w += __shfl_xor(acc.w, 32);
  if (!hw){
    float4 bv = *(const float4*)(bias + l32*4);
    float inv = 1.0f/denom;
    float ox = acc.x*inv + bv.x, oy = acc.y*inv + bv.y;
    float oz = acc.z*inv + bv.z, ow = acc.w*inv + bv.w;
    if (OUTB){  // layer 1: relu + bf16 out
      ox=fmaxf(ox,0.f); oy=fmaxf(oy,0.f); oz=fmaxf(oz,0.f); ow=fmaxf(ow,0.f);
      ushort4 o;
      o.x=f2bf(ox); o.y=f2bf(oy); o.z=f2bf(oz); o.w=f2bf(ow);
      *(ushort4*)(OUTB + (size_t)wid*D + l32*4) = o;
    } else {
      *(float4*)(OUTF + (size_t)wid*D + l32*4) = make_float4(ox,oy,oz,ow);
    }
  }
}

extern "C" void kernel_launch(void* const* d_in, const int* in_sizes, int n_in,
                              void* d_out, int out_size, void* d_ws, size_t ws_size,
                              hipStream_t stream){
  (void)n_in; (void)out_size; (void)ws_size;
  const float* x   = (const float*)d_in[0];
  const int*   ei  = (const int*)d_in[1];
  const float* ea  = (const float*)d_in[2];
  const float* W1  = (const float*)d_in[3];
  const float* a1s = (const float*)d_in[4];
  const float* a1d = (const float*)d_in[5];
  const float* We1 = (const float*)d_in[6];
  const float* ae1 = (const float*)d_in[7];
  const float* b1  = (const float*)d_in[8];
  const float* W2  = (const float*)d_in[9];
  const float* a2s = (const float*)d_in[10];
  const float* a2d = (const float*)d_in[11];
  const float* We2 = (const float*)d_in[12];
  const float* ae2 = (const float*)d_in[13];
  const float* b2  = (const float*)d_in[14];
  int N = in_sizes[0] / D;
  int E = in_sizes[1] / 2;
  const int* srcv = ei;
  const int* dstv = ei + E;
  float* out = (float*)d_out;

  char* p = (char*)d_ws;
  auto allocB = [&](size_t bytes)->void*{
    void* r = (void*)p; p += (bytes + 255) & ~(size_t)255; return r;
  };
  int* deg     = (int*)allocB((size_t)N*4);
  int* cursor  = (int*)allocB((size_t)N*4);
  float* sum1  = (float*)allocB((size_t)N*4);
  float* sum2  = (float*)allocB((size_t)N*4);
  char* zero_end = p;
  float* h     = (float*)allocB((size_t)N*D*4);
  ushort* hb   = (ushort*)allocB((size_t)N*D*2);
  ushort* xb   = (ushort*)allocB((size_t)N*D*2);
  ushort* x2b  = (ushort*)allocB((size_t)N*D*2);
  ushort* Wtb  = (ushort*)allocB((size_t)2*128*128*2);
  float* aeE12 = (float*)allocB((size_t)E*8);
  int4* csr    = (int4*)allocB((size_t)E*16);
  float* as_   = (float*)allocB((size_t)N*4);
  float* ad_   = (float*)allocB((size_t)N*4);
  float* sal   = (float*)allocB((size_t)N*4);
  float* weae  = (float*)allocB(1024);
  int* rowp    = (int*)allocB((size_t)(N+1)*4);
  int* bsum    = (int*)allocB(1024);
  int* boff    = (int*)allocB(1024);

  hipMemsetAsync(deg, 0, (size_t)(zero_end - (char*)deg), stream);

  k_weae<<<64,256,0,stream>>>(We1,ae1,We2,ae2,weae);
  int n8 = N*D/8;
  k_cvt<<<(n8+255)/256,256,0,stream>>>(x, xb, n8);
  k_wt<<<16,256,0,stream>>>(W1, W2, Wtb);
  k_edge<<<2048,256,0,stream>>>(ea,dstv,weae,(float2*)aeE12,sum1,sum2,deg,E);

  int nb = (N + 255)/256;
  k_scan1<<<nb,256,0,stream>>>(deg,bsum,N);
  k_scan2<<<1,256,0,stream>>>(bsum,boff,nb);
  k_scan3<<<nb,256,0,stream>>>(deg,boff,rowp,N,E);
  k_csr<<<(E+255)/256,256,0,stream>>>(srcv,dstv,rowp,cursor,(const float2*)aeE12,csr,E);

  int gemmb = (N + 63)/64;
  int wgrid = (N + 3)/4;

  // layer 1
  k_gemm<<<gemmb,256,0,stream>>>(xb, Wtb,          a1s, a1d, sum1, deg, h, hb, as_, ad_, sal, N);
  k_aggr<<<wgrid,256,0,stream>>>(h, hb, as_, ad_, sal, rowp, csr, 0, b1, nullptr, x2b, N);

  // layer 2
  k_gemm<<<gemmb,256,0,stream>>>(x2b, Wtb + 16384, a2s, a2d, sum2, deg, h, hb, as_, ad_, sal, N);
  k_aggr<<<wgrid,256,0,stream>>>(h, hb, as_, ad_, sal, rowp, csr, 1, b2, out, nullptr, N);
}

// Round 7
// 348.579 us; speedup vs baseline: 1.6197x; 1.0209x over previous
//
#include <hip/hip_runtime.h>
#include <cstdint>

#define D 128
#define NEG 0.2f

typedef __attribute__((ext_vector_type(8))) short bf16x8;
typedef __attribute__((ext_vector_type(4))) float f32x4;

__device__ __forceinline__ float wsum(float v){
#pragma unroll
  for(int m=32;m;m>>=1) v += __shfl_xor(v,m,64);
  return v;
}
__device__ __forceinline__ float lrelu(float a){ return a>0.f ? a : NEG*a; }
__device__ __forceinline__ unsigned short f2bf(float f){
  unsigned int u = __float_as_uint(f);
  u += 0x7fffu + ((u>>16)&1u);
  return (unsigned short)(u>>16);
}
__device__ __forceinline__ float bf2f(unsigned short s){
  return __uint_as_float(((unsigned int)s)<<16);
}

// ---- we_ae[l][s] = dot(We_l[s,:], ae_l) ----
__global__ __launch_bounds__(256) void k_weae(const float* __restrict__ We1, const float* __restrict__ ae1,
                                              const float* __restrict__ We2, const float* __restrict__ ae2,
                                              float* __restrict__ weae){
  int gw  = (blockIdx.x*blockDim.x + threadIdx.x) >> 6;
  int lane = threadIdx.x & 63;
  if (gw >= 256) return;
  const float* We = (gw & 128) ? We2 : We1;
  const float* ae = (gw & 128) ? ae2 : ae1;
  int row = gw & 127;
  float2 v = ((const float2*)(We + (size_t)row*D))[lane];
  float2 a = ((const float2*)ae)[lane];
  float p = wsum(v.x*a.x + v.y*a.y);
  if (!lane) weae[gw] = p;
}

// ---- W[k][c] fp32 -> Wtb[layer][c][k] bf16 (transpose + cvt) ----
__global__ __launch_bounds__(256) void k_wt(const float* __restrict__ W1, const float* __restrict__ W2,
                                            ushort* __restrict__ Wtb){
  __shared__ ushort lds[16][128];
  int b = blockIdx.x;          // 0..15
  int layer = b >> 3;
  int kb = (b & 7) * 16;
  const float* W = layer ? W2 : W1;
  int t = threadIdx.x;
#pragma unroll
  for (int p = 0; p < 8; ++p){
    int idx = t + p*256;
    int kl = idx >> 7, c = idx & 127;
    lds[kl][c] = f2bf(W[(size_t)(kb+kl)*128 + c]);
  }
  __syncthreads();
  int c = t >> 1, kc = (t & 1) * 8;
  ushort tmp[8];
#pragma unroll
  for (int m = 0; m < 8; ++m) tmp[m] = lds[kc+m][c];
  *(uint4*)&Wtb[(size_t)layer*16384 + (size_t)c*128 + kb + kc] = *(uint4*)tmp;
}

// ---- one pass over edge_attr (410MB): a_e both layers + deg histogram (1 atomic/edge) ----
__global__ __launch_bounds__(256) void k_edge(const float* __restrict__ EA, const int* __restrict__ dstv,
                                              const float* __restrict__ weae,
                                              float2* __restrict__ aeE12,
                                              int* __restrict__ deg, int E){
  __shared__ float w1[128], w2[128];
  if (threadIdx.x < 128) w1[threadIdx.x] = weae[threadIdx.x];
  else                   w2[threadIdx.x-128] = weae[threadIdx.x];
  __syncthreads();
  int lane = threadIdx.x & 63;
  int wid  = threadIdx.x >> 6;
  float2 wa = ((const float2*)w1)[lane];
  float2 wb = ((const float2*)w2)[lane];
  for (int e = blockIdx.x*4 + wid; e < E; e += gridDim.x*4){
    float2 v = ((const float2*)(EA + (size_t)e*D))[lane];
    float s1 = wsum(v.x*wa.x + v.y*wa.y);
    float s2 = wsum(v.x*wb.x + v.y*wb.y);
    if (!lane){
      aeE12[e] = make_float2(s1, s2);
      atomicAdd(deg + dstv[e], 1);
    }
  }
}

// ---- scan: deg -> row_ptr (exclusive) ----
__global__ __launch_bounds__(256) void k_scan1(const int* __restrict__ deg, int* __restrict__ bsum, int N){
  __shared__ int s[256];
  int i = blockIdx.x*256 + threadIdx.x;
  s[threadIdx.x] = (i < N) ? deg[i] : 0;
  __syncthreads();
#pragma unroll
  for (int st = 128; st; st >>= 1){
    if (threadIdx.x < st) s[threadIdx.x] += s[threadIdx.x + st];
    __syncthreads();
  }
  if (!threadIdx.x) bsum[blockIdx.x] = s[0];
}
__global__ __launch_bounds__(256) void k_scan2(const int* __restrict__ bsum, int* __restrict__ boff, int NB){
  __shared__ int s[256];
  int t = threadIdx.x;
  int v = (t < NB) ? bsum[t] : 0;
  s[t] = v; __syncthreads();
  for (int d = 1; d < 256; d <<= 1){
    int x = (t >= d) ? s[t-d] : 0;
    __syncthreads();
    s[t] += x;
    __syncthreads();
  }
  boff[t] = s[t] - v;
}
__global__ __launch_bounds__(256) void k_scan3(const int* __restrict__ deg, const int* __restrict__ boff,
                                               int* __restrict__ rowp, int N, int E){
  __shared__ int s[256];
  int t = threadIdx.x;
  int i = blockIdx.x*256 + t;
  int v = (i < N) ? deg[i] : 0;
  s[t] = v; __syncthreads();
  for (int d = 1; d < 256; d <<= 1){
    int x = (t >= d) ? s[t-d] : 0;
    __syncthreads();
    s[t] += x;
    __syncthreads();
  }
  if (i < N) rowp[i] = boff[blockIdx.x] + s[t] - v;
  if (i == N-1) rowp[N] = E;
}

// ---- CSR fill: dst-sorted packed records {src, ae_l1, ae_l2, dst} ----
__global__ __launch_bounds__(256) void k_csr(const int* __restrict__ srcv, const int* __restrict__ dstv,
                                             const int* __restrict__ rowp, int* __restrict__ cursor,
                                             const float2* __restrict__ aeE12,
                                             int4* __restrict__ csr, int E){
  int e = blockIdx.x*256 + threadIdx.x;
  if (e >= E) return;
  int d = dstv[e];
  int pos = rowp[d] + atomicAdd(cursor + d, 1);
  float2 ae = aeE12[e];
  int4 rec;
  rec.x = srcv[e];
  rec.y = __float_as_int(ae.x);
  rec.z = __float_as_int(ae.y);
  rec.w = d;
  csr[pos] = rec;
}

// ---- segment sums of a_e over dst neighborhoods (replaces atomic sum1/sum2) ----
__global__ __launch_bounds__(256) void k_sums(const int* __restrict__ rowp, const int4* __restrict__ csr,
                                              float* __restrict__ sum1, float* __restrict__ sum2, int N){
  int wid  = (blockIdx.x*blockDim.x + threadIdx.x) >> 6;
  int lane = threadIdx.x & 63;
  if (wid >= N) return;
  int p0 = rowp[wid], p1 = rowp[wid+1];
  float s1 = 0.f, s2 = 0.f;
  for (int p = p0 + lane; p < p1; p += 64){
    int4 r = csr[p];
    s1 += __int_as_float(r.y);
    s2 += __int_as_float(r.z);
  }
  s1 = wsum(s1); s2 = wsum(s2);
  if (!lane){ sum1[wid] = s1; sum2[wid] = s2; }
}

// ---- MFMA GEMM: H = X @ W (bf16 in, fp32 out) + fused a_s/a_d/sal epilogue + Hb bf16 out ----
// Xf (fp32) or Xb (bf16) as input; converts during staging if Xf != null.
__global__ __launch_bounds__(256) void k_gemm(const float* __restrict__ Xf, const ushort* __restrict__ Xb,
                                              const ushort* __restrict__ Wtb,
                                              const float* __restrict__ atts, const float* __restrict__ attd,
                                              const float* __restrict__ sum_ae, const int* __restrict__ rowp,
                                              float* __restrict__ H, ushort* __restrict__ Hb,
                                              float* __restrict__ a_s, float* __restrict__ a_d,
                                              float* __restrict__ sal, int N){
  __shared__ ushort xsb[64*136];
  __shared__ ushort wsb[128*136];
  int tid = threadIdx.x;
  int rowbase = blockIdx.x*64;
  if (Xf){
#pragma unroll
    for (int i = 0; i < 4; ++i){
      int idx = tid + i*256;
      int r = idx >> 4, ch = idx & 15;
      int gr = rowbase + r;
      int grc = (gr < N) ? gr : 0;
      const float4* src = (const float4*)(Xf + (size_t)grc*128 + ch*8);
      float4 a = src[0], b = src[1];
      uint4 o;
      o.x = (unsigned)f2bf(a.x) | ((unsigned)f2bf(a.y)<<16);
      o.y = (unsigned)f2bf(a.z) | ((unsigned)f2bf(a.w)<<16);
      o.z = (unsigned)f2bf(b.x) | ((unsigned)f2bf(b.y)<<16);
      o.w = (unsigned)f2bf(b.z) | ((unsigned)f2bf(b.w)<<16);
      *(uint4*)&xsb[r*136 + ch*8] = o;
    }
  } else {
#pragma unroll
    for (int i = 0; i < 4; ++i){
      int idx = tid + i*256;
      int r = idx >> 4, ch = idx & 15;
      int gr = rowbase + r;
      int grc = (gr < N) ? gr : 0;
      *(uint4*)&xsb[r*136 + ch*8] = *(const uint4*)&Xb[(size_t)grc*128 + ch*8];
    }
  }
#pragma unroll
  for (int i = 0; i < 8; ++i){
    int idx = tid + i*256;
    int c = idx >> 4, ch = idx & 15;
    *(uint4*)&wsb[c*136 + ch*8] = *(const uint4*)&Wtb[(size_t)c*128 + ch*8];
  }
  __syncthreads();

  int lane = tid & 63;
  int w    = tid >> 6;
  int l15  = lane & 15;
  int lg   = lane >> 4;
  int r0   = w*16;

  f32x4 acc[8];
#pragma unroll
  for (int ct = 0; ct < 8; ++ct) acc[ct] = (f32x4){0.f,0.f,0.f,0.f};

#pragma unroll
  for (int ks = 0; ks < 4; ++ks){
    bf16x8 af = *(const bf16x8*)&xsb[(r0 + l15)*136 + ks*32 + lg*8];
#pragma unroll
    for (int ct = 0; ct < 8; ++ct){
      bf16x8 bfr = *(const bf16x8*)&wsb[(ct*16 + l15)*136 + ks*32 + lg*8];
      acc[ct] = __builtin_amdgcn_mfma_f32_16x16x32_bf16(af, bfr, acc[ct], 0, 0, 0);
    }
  }

  float attsv[8], attdv[8];
#pragma unroll
  for (int ct = 0; ct < 8; ++ct){
    attsv[ct] = atts[ct*16 + l15];
    attdv[ct] = attd[ct*16 + l15];
  }
  float ps[4] = {0,0,0,0}, pd[4] = {0,0,0,0};
#pragma unroll
  for (int ct = 0; ct < 8; ++ct)
#pragma unroll
    for (int j = 0; j < 4; ++j){
      ps[j] += acc[ct][j]*attsv[ct];
      pd[j] += acc[ct][j]*attdv[ct];
    }
#pragma unroll
  for (int m = 1; m <= 8; m <<= 1)
#pragma unroll
    for (int j = 0; j < 4; ++j){
      ps[j] += __shfl_xor(ps[j], m, 64);
      pd[j] += __shfl_xor(pd[j], m, 64);
    }
#pragma unroll
  for (int j = 0; j < 4; ++j){
    int gr = rowbase + r0 + lg*4 + j;
    if (gr < N){
#pragma unroll
      for (int ct = 0; ct < 8; ++ct){
        int col = ct*16 + l15;
        float v = acc[ct][j];
        H [(size_t)gr*128 + col] = v;
        Hb[(size_t)gr*128 + col] = f2bf(v);
      }
      if (l15 == 0){
        a_s[gr] = ps[j];
        a_d[gr] = pd[j];
        int dg = rowp[gr+1] - rowp[gr];
        float la = sum_ae[gr] / fmaxf((float)dg, 1.0f);
        sal[gr] = lrelu(ps[j] + pd[j] + la);
      }
    }
  }
}

// ---- edge-parallel exp pass: sx[p] = {src, exp(lrelu(a_s[src]+a_d[dst]+ae))} ----
__global__ __launch_bounds__(256) void k_ex(const int4* __restrict__ csr,
                                            const float* __restrict__ a_s, const float* __restrict__ a_d,
                                            int layer, uint2* __restrict__ sx, int E){
  int p = blockIdx.x*256 + threadIdx.x;
  if (p >= E) return;
  int4 rec = csr[p];
  float ae = __int_as_float(layer ? rec.z : rec.y);
  float ex = __expf(lrelu(a_s[rec.x] + a_d[rec.w] + ae));
  sx[p] = make_uint2((unsigned)rec.x, __float_as_uint(ex));
}

// ---- aggregation v5: one wave per dst; sequential {src,ex} read; LDS broadcast;
//      16 row-gathers in flight per wave; zero-padded tails (wave-uniform loops) ----
__global__ __launch_bounds__(256) void k_aggr(const float* __restrict__ H, const ushort* __restrict__ Hb,
                                              const float* __restrict__ sal,
                                              const int* __restrict__ rowp, const uint2* __restrict__ sx,
                                              const float* __restrict__ bias,
                                              float* __restrict__ OUTF, ushort* __restrict__ OUTB, int N){
  __shared__ uint2 lse[4][64];
  int wslot = threadIdx.x >> 6;
  int wid  = (blockIdx.x*blockDim.x + threadIdx.x) >> 6;
  int lane = threadIdx.x & 63;
  if (wid >= N) return;
  int p0 = rowp[wid], p1 = rowp[wid+1];
  int l32 = lane & 31;
  int hw  = lane >> 5;
  float ex_self = __expf(sal[wid]);
  float denom = ex_self;
  float4 acc = {0.f,0.f,0.f,0.f};
  if (!hw){
    float4 hs = *(const float4*)(H + (size_t)wid*D + l32*4);
    acc.x = ex_self*hs.x; acc.y = ex_self*hs.y; acc.z = ex_self*hs.z; acc.w = ex_self*hs.w;
  }
  for (int c0 = p0; c0 < p1; c0 += 64){
    int p = c0 + lane;
    bool valid = p < p1;
    uint2 se = valid ? sx[p] : make_uint2(0u, 0u);
    denom += wsum(__uint_as_float(se.y));
    lse[wslot][lane] = se;
    int cnt = p1 - c0; if (cnt > 64) cnt = 64;   // wave-uniform
    for (int it = 0; it*16 < cnt; ++it){
      int base = it*16 + hw*8;
#pragma unroll
      for (int k = 0; k < 8; ++k){
        uint2 t = lse[wslot][base + k];
        float w2 = __uint_as_float(t.y);
        ushort4 u = *(const ushort4*)(Hb + (size_t)t.x*D + l32*4);
        acc.x += w2*bf2f(u.x); acc.y += w2*bf2f(u.y);
        acc.z += w2*bf2f(u.z); acc.w += w2*bf2f(u.w);
      }
    }
  }
  acc.x += __shfl_xor(acc.x, 32);
  acc.y += __shfl_xor(acc.y, 32);
  acc.z += __shfl_xor(acc.z, 32);
  acc.w += __shfl_xor(acc.w, 32);
  if (!hw){
    float4 bv = *(const float4*)(bias + l32*4);
    float inv = 1.0f/denom;
    float ox = acc.x*inv + bv.x, oy = acc.y*inv + bv.y;
    float oz = acc.z*inv + bv.z, ow = acc.w*inv + bv.w;
    if (OUTB){  // layer 1: relu + bf16 out
      ox=fmaxf(ox,0.f); oy=fmaxf(oy,0.f); oz=fmaxf(oz,0.f); ow=fmaxf(ow,0.f);
      ushort4 o;
      o.x=f2bf(ox); o.y=f2bf(oy); o.z=f2bf(oz); o.w=f2bf(ow);
      *(ushort4*)(OUTB + (size_t)wid*D + l32*4) = o;
    } else {
      *(float4*)(OUTF + (size_t)wid*D + l32*4) = make_float4(ox,oy,oz,ow);
    }
  }
}

extern "C" void kernel_launch(void* const* d_in, const int* in_sizes, int n_in,
                              void* d_out, int out_size, void* d_ws, size_t ws_size,
                              hipStream_t stream){
  (void)n_in; (void)out_size; (void)ws_size;
  const float* x   = (const float*)d_in[0];
  const int*   ei  = (const int*)d_in[1];
  const float* ea  = (const float*)d_in[2];
  const float* W1  = (const float*)d_in[3];
  const float* a1s = (const float*)d_in[4];
  const float* a1d = (const float*)d_in[5];
  const float* We1 = (const float*)d_in[6];
  const float* ae1 = (const float*)d_in[7];
  const float* b1  = (const float*)d_in[8];
  const float* W2  = (const float*)d_in[9];
  const float* a2s = (const float*)d_in[10];
  const float* a2d = (const float*)d_in[11];
  const float* We2 = (const float*)d_in[12];
  const float* ae2 = (const float*)d_in[13];
  const float* b2  = (const float*)d_in[14];
  int N = in_sizes[0] / D;
  int E = in_sizes[1] / 2;
  const int* srcv = ei;
  const int* dstv = ei + E;
  float* out = (float*)d_out;

  char* p = (char*)d_ws;
  auto allocB = [&](size_t bytes)->void*{
    void* r = (void*)p; p += (bytes + 255) & ~(size_t)255; return r;
  };
  int* deg     = (int*)allocB((size_t)N*4);
  int* cursor  = (int*)allocB((size_t)N*4);
  char* zero_end = p;
  float* sum1  = (float*)allocB((size_t)N*4);
  float* sum2  = (float*)allocB((size_t)N*4);
  float* h     = (float*)allocB((size_t)N*D*4);
  ushort* hb   = (ushort*)allocB((size_t)N*D*2);
  ushort* x2b  = (ushort*)allocB((size_t)N*D*2);
  ushort* Wtb  = (ushort*)allocB((size_t)2*128*128*2);
  float* aeE12 = (float*)allocB((size_t)E*8);
  int4* csr    = (int4*)allocB((size_t)E*16);
  uint2* sx    = (uint2*)allocB((size_t)E*8);
  float* as_   = (float*)allocB((size_t)N*4);
  float* ad_   = (float*)allocB((size_t)N*4);
  float* sal   = (float*)allocB((size_t)N*4);
  float* weae  = (float*)allocB(1024);
  int* rowp    = (int*)allocB((size_t)(N+1)*4);
  int* bsum    = (int*)allocB(1024);
  int* boff    = (int*)allocB(1024);

  hipMemsetAsync(deg, 0, (size_t)(zero_end - (char*)deg), stream);

  k_weae<<<64,256,0,stream>>>(We1,ae1,We2,ae2,weae);
  k_wt<<<16,256,0,stream>>>(W1, W2, Wtb);
  k_edge<<<2048,256,0,stream>>>(ea,dstv,weae,(float2*)aeE12,deg,E);

  int nb = (N + 255)/256;
  k_scan1<<<nb,256,0,stream>>>(deg,bsum,N);
  k_scan2<<<1,256,0,stream>>>(bsum,boff,nb);
  k_scan3<<<nb,256,0,stream>>>(deg,boff,rowp,N,E);
  k_csr<<<(E+255)/256,256,0,stream>>>(srcv,dstv,rowp,cursor,(const float2*)aeE12,csr,E);

  int wgrid = (N + 3)/4;
  k_sums<<<wgrid,256,0,stream>>>(rowp, csr, sum1, sum2, N);

  int gemmb = (N + 63)/64;
  int exb   = (E + 255)/256;

  // layer 1
  k_gemm<<<gemmb,256,0,stream>>>(x, nullptr, Wtb,          a1s, a1d, sum1, rowp, h, hb, as_, ad_, sal, N);
  k_ex  <<<exb,  256,0,stream>>>(csr, as_, ad_, 0, sx, E);
  k_aggr<<<wgrid,256,0,stream>>>(h, hb, sal, rowp, sx, b1, nullptr, x2b, N);

  // layer 2
  k_gemm<<<gemmb,256,0,stream>>>(nullptr, x2b, Wtb + 16384, a2s, a2d, sum2, rowp, h, hb, as_, ad_, sal, N);
  k_ex  <<<exb,  256,0,stream>>>(csr, as_, ad_, 1, sx, E);
  k_aggr<<<wgrid,256,0,stream>>>(h, hb, sal, rowp, sx, b2, out, nullptr, N);
}

// Round 9
// 271.413 us; speedup vs baseline: 2.0802x; 1.2843x over previous
//
#include <hip/hip_runtime.h>
#include <cstdint>

#define D 128
#define NEG 0.2f

typedef __attribute__((ext_vector_type(8))) short bf16x8;
typedef __attribute__((ext_vector_type(4))) float f32x4;

__device__ __forceinline__ float wsum(float v){
#pragma unroll
  for(int m=32;m;m>>=1) v += __shfl_xor(v,m,64);
  return v;
}
__device__ __forceinline__ float lrelu(float a){ return a>0.f ? a : NEG*a; }
__device__ __forceinline__ unsigned short f2bf(float f){
  unsigned int u = __float_as_uint(f);
  u += 0x7fffu + ((u>>16)&1u);
  return (unsigned short)(u>>16);
}
__device__ __forceinline__ float bf2f(unsigned short s){
  return __uint_as_float(((unsigned int)s)<<16);
}

// ---- fused init: blocks 0..63 -> weae (256 wave-rows); blocks 64..79 -> W transpose+cvt ----
__global__ __launch_bounds__(256) void k_init(const float* __restrict__ We1, const float* __restrict__ ae1,
                                              const float* __restrict__ We2, const float* __restrict__ ae2,
                                              const float* __restrict__ W1,  const float* __restrict__ W2,
                                              float* __restrict__ weae, ushort* __restrict__ Wtb){
  __shared__ ushort lds[16][128];
  if (blockIdx.x < 64){
    int gw  = (blockIdx.x*256 + threadIdx.x) >> 6;
    int lane = threadIdx.x & 63;
    const float* We = (gw & 128) ? We2 : We1;
    const float* ae = (gw & 128) ? ae2 : ae1;
    int row = gw & 127;
    float2 v = ((const float2*)(We + (size_t)row*D))[lane];
    float2 a = ((const float2*)ae)[lane];
    float p = wsum(v.x*a.x + v.y*a.y);
    if (!lane) weae[gw] = p;
  } else {
    int b = blockIdx.x - 64;     // 0..15
    int layer = b >> 3;
    int kb = (b & 7) * 16;
    const float* W = layer ? W2 : W1;
    int t = threadIdx.x;
#pragma unroll
    for (int p = 0; p < 8; ++p){
      int idx = t + p*256;
      int kl = idx >> 7, c = idx & 127;
      lds[kl][c] = f2bf(W[(size_t)(kb+kl)*128 + c]);
    }
    __syncthreads();
    int c = t >> 1, kc = (t & 1) * 8;
    ushort tmp[8];
#pragma unroll
    for (int m = 0; m < 8; ++m) tmp[m] = lds[kc+m][c];
    *(uint4*)&Wtb[(size_t)layer*16384 + (size_t)c*128 + kb + kc] = *(uint4*)tmp;
  }
}

// ---- edge pass v2: 8 lanes per edge, 8 edges per wave; 6 shfl per edge-group ----
__global__ __launch_bounds__(256) void k_edge(const float* __restrict__ EA, const int* __restrict__ dstv,
                                              const float* __restrict__ weae,
                                              float2* __restrict__ aeE12,
                                              int* __restrict__ deg, int E){
  int l   = threadIdx.x & 63;
  int sub = l & 7;
  int grp = l >> 3;
  float4 w1v[4], w2v[4];
#pragma unroll
  for (int k = 0; k < 4; ++k){
    w1v[k] = ((const float4*)weae)[sub + 8*k];
    w2v[k] = ((const float4*)weae)[32 + sub + 8*k];
  }
  int gwave  = (blockIdx.x*blockDim.x + threadIdx.x) >> 6;
  int nwaves = (gridDim.x*blockDim.x) >> 6;
  for (int e0 = gwave*8; e0 < E; e0 += nwaves*8){
    int e = e0 + grp;
    const float4* row = (const float4*)(EA + (size_t)e*D);
    float s1 = 0.f, s2 = 0.f;
#pragma unroll
    for (int k = 0; k < 4; ++k){
      float4 v = row[sub + 8*k];
      s1 += v.x*w1v[k].x + v.y*w1v[k].y + v.z*w1v[k].z + v.w*w1v[k].w;
      s2 += v.x*w2v[k].x + v.y*w2v[k].y + v.z*w2v[k].z + v.w*w2v[k].w;
    }
#pragma unroll
    for (int m = 1; m <= 4; m <<= 1){
      s1 += __shfl_xor(s1, m, 64);
      s2 += __shfl_xor(s2, m, 64);
    }
    if (!sub){
      aeE12[e] = make_float2(s1, s2);
      atomicAdd(deg + dstv[e], 1);
    }
  }
}

// ---- scan: deg -> row_ptr (exclusive) ----
__global__ __launch_bounds__(256) void k_scan1(const int* __restrict__ deg, int* __restrict__ bsum, int N){
  __shared__ int s[256];
  int i = blockIdx.x*256 + threadIdx.x;
  s[threadIdx.x] = (i < N) ? deg[i] : 0;
  __syncthreads();
#pragma unroll
  for (int st = 128; st; st >>= 1){
    if (threadIdx.x < st) s[threadIdx.x] += s[threadIdx.x + st];
    __syncthreads();
  }
  if (!threadIdx.x) bsum[blockIdx.x] = s[0];
}
__global__ __launch_bounds__(256) void k_scan2(const int* __restrict__ bsum, int* __restrict__ boff, int NB){
  __shared__ int s[256];
  int t = threadIdx.x;
  int v = (t < NB) ? bsum[t] : 0;
  s[t] = v; __syncthreads();
  for (int d = 1; d < 256; d <<= 1){
    int x = (t >= d) ? s[t-d] : 0;
    __syncthreads();
    s[t] += x;
    __syncthreads();
  }
  boff[t] = s[t] - v;
}
__global__ __launch_bounds__(256) void k_scan3(const int* __restrict__ deg, const int* __restrict__ boff,
                                               int* __restrict__ rowp, int N, int E){
  __shared__ int s[256];
  int t = threadIdx.x;
  int i = blockIdx.x*256 + t;
  int v = (i < N) ? deg[i] : 0;
  s[t] = v; __syncthreads();
  for (int d = 1; d < 256; d <<= 1){
    int x = (t >= d) ? s[t-d] : 0;
    __syncthreads();
    s[t] += x;
    __syncthreads();
  }
  if (i < N) rowp[i] = boff[blockIdx.x] + s[t] - v;
  if (i == N-1) rowp[N] = E;
}

// ---- CSR fill: dst-sorted packed records {src, ae_l1, ae_l2, dst} ----
__global__ __launch_bounds__(256) void k_csr(const int* __restrict__ srcv, const int* __restrict__ dstv,
                                             const int* __restrict__ rowp, int* __restrict__ cursor,
                                             const float2* __restrict__ aeE12,
                                             int4* __restrict__ csr, int E){
  int e = blockIdx.x*256 + threadIdx.x;
  if (e >= E) return;
  int d = dstv[e];
  int pos = rowp[d] + atomicAdd(cursor + d, 1);
  float2 ae = aeE12[e];
  int4 rec;
  rec.x = srcv[e];
  rec.y = __float_as_int(ae.x);
  rec.z = __float_as_int(ae.y);
  rec.w = d;
  csr[pos] = rec;
}

// ---- MFMA GEMM: Hb = bf16(X @ W) + fused a_s/a_d epilogue; coalesced bf16 store via LDS repack ----
__global__ __launch_bounds__(256) void k_gemm(const float* __restrict__ Xf, const ushort* __restrict__ Xb,
                                              const ushort* __restrict__ Wtb,
                                              const float* __restrict__ atts, const float* __restrict__ attd,
                                              ushort* __restrict__ Hb,
                                              float* __restrict__ a_s, float* __restrict__ a_d, int N){
  __shared__ ushort xsb[64*136];
  __shared__ ushort wsb[128*136];
  int tid = threadIdx.x;
  int rowbase = blockIdx.x*64;
  if (Xf){
#pragma unroll
    for (int i = 0; i < 4; ++i){
      int idx = tid + i*256;
      int r = idx >> 4, ch = idx & 15;
      int gr = rowbase + r;
      int grc = (gr < N) ? gr : 0;
      const float4* src = (const float4*)(Xf + (size_t)grc*128 + ch*8);
      float4 a = src[0], b = src[1];
      uint4 o;
      o.x = (unsigned)f2bf(a.x) | ((unsigned)f2bf(a.y)<<16);
      o.y = (unsigned)f2bf(a.z) | ((unsigned)f2bf(a.w)<<16);
      o.z = (unsigned)f2bf(b.x) | ((unsigned)f2bf(b.y)<<16);
      o.w = (unsigned)f2bf(b.z) | ((unsigned)f2bf(b.w)<<16);
      *(uint4*)&xsb[r*136 + ch*8] = o;
    }
  } else {
#pragma unroll
    for (int i = 0; i < 4; ++i){
      int idx = tid + i*256;
      int r = idx >> 4, ch = idx & 15;
      int gr = rowbase + r;
      int grc = (gr < N) ? gr : 0;
      *(uint4*)&xsb[r*136 + ch*8] = *(const uint4*)&Xb[(size_t)grc*128 + ch*8];
    }
  }
#pragma unroll
  for (int i = 0; i < 8; ++i){
    int idx = tid + i*256;
    int c = idx >> 4, ch = idx & 15;
    *(uint4*)&wsb[c*136 + ch*8] = *(const uint4*)&Wtb[(size_t)c*128 + ch*8];
  }
  __syncthreads();

  int lane = tid & 63;
  int w    = tid >> 6;
  int l15  = lane & 15;
  int lg   = lane >> 4;
  int r0   = w*16;

  f32x4 acc[8];
#pragma unroll
  for (int ct = 0; ct < 8; ++ct) acc[ct] = (f32x4){0.f,0.f,0.f,0.f};

#pragma unroll
  for (int ks = 0; ks < 4; ++ks){
    bf16x8 af = *(const bf16x8*)&xsb[(r0 + l15)*136 + ks*32 + lg*8];
#pragma unroll
    for (int ct = 0; ct < 8; ++ct){
      bf16x8 bfr = *(const bf16x8*)&wsb[(ct*16 + l15)*136 + ks*32 + lg*8];
      acc[ct] = __builtin_amdgcn_mfma_f32_16x16x32_bf16(af, bfr, acc[ct], 0, 0, 0);
    }
  }

  // a_s/a_d epilogue
  float attsv[8], attdv[8];
#pragma unroll
  for (int ct = 0; ct < 8; ++ct){
    attsv[ct] = atts[ct*16 + l15];
    attdv[ct] = attd[ct*16 + l15];
  }
  float ps[4] = {0,0,0,0}, pd[4] = {0,0,0,0};
#pragma unroll
  for (int ct = 0; ct < 8; ++ct)
#pragma unroll
    for (int j = 0; j < 4; ++j){
      ps[j] += acc[ct][j]*attsv[ct];
      pd[j] += acc[ct][j]*attdv[ct];
    }
#pragma unroll
  for (int m = 1; m <= 8; m <<= 1)
#pragma unroll
    for (int j = 0; j < 4; ++j){
      ps[j] += __shfl_xor(ps[j], m, 64);
      pd[j] += __shfl_xor(pd[j], m, 64);
    }
#pragma unroll
  for (int j = 0; j < 4; ++j){
    int gr = rowbase + r0 + lg*4 + j;
    if (gr < N && l15 == 0){
      a_s[gr] = ps[j];
      a_d[gr] = pd[j];
    }
  }
  // repack acc -> xsb (own rows only) then coalesced store
#pragma unroll
  for (int ct = 0; ct < 8; ++ct)
#pragma unroll
    for (int j = 0; j < 4; ++j){
      int r = r0 + lg*4 + j;
      xsb[r*136 + ct*16 + l15] = f2bf(acc[ct][j]);
    }
  __syncthreads();
#pragma unroll
  for (int i = 0; i < 4; ++i){
    int idx = tid + i*256;
    int r = idx >> 4, ch = idx & 15;
    int gr = rowbase + r;
    if (gr < N)
      *(uint4*)&Hb[(size_t)gr*128 + ch*8] = *(const uint4*)&xsb[r*136 + ch*8];
  }
}

// ---- aggregation v6: fully fused (exp + sum_ae + self-loop + softmax + gather) ----
__global__ __launch_bounds__(256) void k_aggr(const ushort* __restrict__ Hb,
                                              const float* __restrict__ a_s, const float* __restrict__ a_d,
                                              const int* __restrict__ rowp, const int4* __restrict__ csr,
                                              int layer,
                                              const float* __restrict__ bias,
                                              float* __restrict__ OUTF, ushort* __restrict__ OUTB, int N){
  __shared__ uint2 lse[4][64];
  int wslot = threadIdx.x >> 6;
  int wid  = (blockIdx.x*blockDim.x + threadIdx.x) >> 6;
  int lane = threadIdx.x & 63;
  if (wid >= N) return;
  int p0 = rowp[wid], p1 = rowp[wid+1];
  float as_own = a_s[wid];
  float ad     = a_d[wid];
  int l32 = lane & 31;
  int hw  = lane >> 5;
  // issue self-row load early
  ushort4 uself = make_ushort4(0,0,0,0);
  if (!hw) uself = *(const ushort4*)(Hb + (size_t)wid*D + l32*4);
  float denom = 0.f, sumae = 0.f;
  float4 acc = {0.f,0.f,0.f,0.f};
  for (int c0 = p0; c0 < p1; c0 += 64){
    int p = c0 + lane;
    bool valid = p < p1;
    int4 rec = valid ? csr[p] : make_int4(0,0,0,0);
    float ae = valid ? __int_as_float(layer ? rec.z : rec.y) : 0.f;
    float ex = valid ? __expf(lrelu(a_s[rec.x] + ad + ae)) : 0.f;
    sumae += wsum(ae);
    denom += wsum(ex);
    lse[wslot][lane] = make_uint2((unsigned)rec.x, __float_as_uint(ex));
    int cnt = p1 - c0; if (cnt > 64) cnt = 64;   // wave-uniform
    for (int it = 0; it*16 < cnt; ++it){
      int base = it*16 + hw*8;
#pragma unroll
      for (int k = 0; k < 8; ++k){
        uint2 t = lse[wslot][base + k];
        float w2 = __uint_as_float(t.y);
        ushort4 u = *(const ushort4*)(Hb + (size_t)t.x*D + l32*4);
        acc.x += w2*bf2f(u.x); acc.y += w2*bf2f(u.y);
        acc.z += w2*bf2f(u.z); acc.w += w2*bf2f(u.w);
      }
    }
  }
  // self loop: alpha = lrelu(a_s + a_d + mean(ae))
  float dg = (float)(p1 - p0);
  float la = sumae / fmaxf(dg, 1.0f);
  float ex_self = __expf(lrelu(as_own + ad + la));
  denom += ex_self;
  // combine halves, add self, bias, store
  acc.x += __shfl_xor(acc.x, 32);
  acc.y += __shfl_xor(acc.y, 32);
  acc.z += __shfl_xor(acc.z, 32);
  acc.w += __shfl_xor(acc.w, 32);
  if (!hw){
    acc.x += ex_self*bf2f(uself.x); acc.y += ex_self*bf2f(uself.y);
    acc.z += ex_self*bf2f(uself.z); acc.w += ex_self*bf2f(uself.w);
    float4 bv = *(const float4*)(bias + l32*4);
    float inv = 1.0f/denom;
    float ox = acc.x*inv + bv.x, oy = acc.y*inv + bv.y;
    float oz = acc.z*inv + bv.z, ow = acc.w*inv + bv.w;
    if (OUTB){  // layer 1: relu + bf16 out
      ox=fmaxf(ox,0.f); oy=fmaxf(oy,0.f); oz=fmaxf(oz,0.f); ow=fmaxf(ow,0.f);
      ushort4 o;
      o.x=f2bf(ox); o.y=f2bf(oy); o.z=f2bf(oz); o.w=f2bf(ow);
      *(ushort4*)(OUTB + (size_t)wid*D + l32*4) = o;
    } else {
      *(float4*)(OUTF + (size_t)wid*D + l32*4) = make_float4(ox,oy,oz,ow);
    }
  }
}

extern "C" void kernel_launch(void* const* d_in, const int* in_sizes, int n_in,
                              void* d_out, int out_size, void* d_ws, size_t ws_size,
                              hipStream_t stream){
  (void)n_in; (void)out_size; (void)ws_size;
  const float* x   = (const float*)d_in[0];
  const int*   ei  = (const int*)d_in[1];
  const float* ea  = (const float*)d_in[2];
  const float* W1  = (const float*)d_in[3];
  const float* a1s = (const float*)d_in[4];
  const float* a1d = (const float*)d_in[5];
  const float* We1 = (const float*)d_in[6];
  const float* ae1 = (const float*)d_in[7];
  const float* b1  = (const float*)d_in[8];
  const float* W2  = (const float*)d_in[9];
  const float* a2s = (const float*)d_in[10];
  const float* a2d = (const float*)d_in[11];
  const float* We2 = (const float*)d_in[12];
  const float* ae2 = (const float*)d_in[13];
  const float* b2  = (const float*)d_in[14];
  int N = in_sizes[0] / D;
  int E = in_sizes[1] / 2;
  const int* srcv = ei;
  const int* dstv = ei + E;
  float* out = (float*)d_out;

  char* p = (char*)d_ws;
  auto allocB = [&](size_t bytes)->void*{
    void* r = (void*)p; p += (bytes + 255) & ~(size_t)255; return r;
  };
  int* deg     = (int*)allocB((size_t)N*4);
  int* cursor  = (int*)allocB((size_t)N*4);
  char* zero_end = p;
  ushort* hb   = (ushort*)allocB((size_t)N*D*2);
  ushort* x2b  = (ushort*)allocB((size_t)N*D*2);
  ushort* Wtb  = (ushort*)allocB((size_t)2*128*128*2);
  float* aeE12 = (float*)allocB((size_t)E*8);
  int4* csr    = (int4*)allocB((size_t)E*16);
  float* as_   = (float*)allocB((size_t)N*4);
  float* ad_   = (float*)allocB((size_t)N*4);
  float* weae  = (float*)allocB(1024);
  int* rowp    = (int*)allocB((size_t)(N+1)*4);
  int* bsum    = (int*)allocB(1024);
  int* boff    = (int*)allocB(1024);

  hipMemsetAsync(deg, 0, (size_t)(zero_end - (char*)deg), stream);

  k_init<<<80,256,0,stream>>>(We1,ae1,We2,ae2,W1,W2,weae,Wtb);
  k_edge<<<2048,256,0,stream>>>(ea,dstv,weae,(float2*)aeE12,deg,E);

  int nb = (N + 255)/256;
  k_scan1<<<nb,256,0,stream>>>(deg,bsum,N);
  k_scan2<<<1,256,0,stream>>>(bsum,boff,nb);
  k_scan3<<<nb,256,0,stream>>>(deg,boff,rowp,N,E);
  k_csr<<<(E+255)/256,256,0,stream>>>(srcv,dstv,rowp,cursor,(const float2*)aeE12,csr,E);

  int gemmb = (N + 63)/64;
  int wgrid = (N + 3)/4;

  // layer 1
  k_gemm<<<gemmb,256,0,stream>>>(x, nullptr, Wtb,          a1s, a1d, hb, as_, ad_, N);
  k_aggr<<<wgrid,256,0,stream>>>(hb, as_, ad_, rowp, csr, 0, b1, nullptr, x2b, N);

  // layer 2
  k_gemm<<<gemmb,256,0,stream>>>(nullptr, x2b, Wtb + 16384, a2s, a2d, hb, as_, ad_, N);
  k_aggr<<<wgrid,256,0,stream>>>(hb, as_, ad_, rowp, csr, 1, b2, out, nullptr, N);
}